// Round 1
// 316.728 us; speedup vs baseline: 1.0093x; 1.0093x over previous
//
#include <hip/hip_runtime.h>

// Attention_6219112645023 — fp32 in / fp32 out, bf16 internal compute (MFMA).
// B=2, T=2048, DIM=2048, NH=32, NKV=8, HD=64. Causal GQA + RoPE + projections.
// Pipeline: cvt5 -> fused QKV gemm -> transpose(V) -> flash attn -> O gemm.
// R7: BK=64 (two 32-col LDS panels, barriers halved), hw-sin/cos RoPE,
// O-projection as 128x64-tile gemm_out64 (1024 blocks = 4/CU).
// R8: attn restructured — swapped QK^T (mfma(K,Q)) makes P lane-local in q;
// key axis permuted (slot(k)=32(k>>5)+8((k>>2)&3)+4((k>>4)&1)+(k&3)) so each
// lane's packed P words ARE its PV A-fragment: Ps LDS eliminated entirely
// (no stores/reads/lgkm wait, -9KB LDS, kills 4-way Ps write conflicts).
// V staging writes slot-permuted (4x ds_write_b64). P pack via v_perm_b32.

typedef unsigned short u16;
typedef __attribute__((ext_vector_type(8))) short bf16x8;  // 8 bf16 in 4 VGPRs
typedef __attribute__((ext_vector_type(4))) float f32x4;
typedef __attribute__((ext_vector_type(4))) unsigned short u16x4;

constexpr int T_SEQ = 2048;
constexpr int DIMC  = 2048;
constexpr int NHEAD = 32;
constexpr int HDIM  = 64;
constexpr int KVDIM = 512;   // NKV * HDIM
constexpr int BATCH = 2;

__device__ __forceinline__ u16 f2bf(float f) {
    union { float f; unsigned int i; } v; v.f = f;
    unsigned int r = v.i + 0x7FFFu + ((v.i >> 16) & 1u);   // RNE
    return (u16)(r >> 16);
}

// pack two f32 -> (bf16 lo = e0, bf16 hi = e1), truncating (P in [0,1]).
// v_perm_b32: one VALU op, replaces shift/and/or chains.
__device__ __forceinline__ unsigned int pack2_bf16(float e0, float e1) {
    return __builtin_amdgcn_perm(__float_as_uint(e1), __float_as_uint(e0),
                                 0x07060302u);
}

typedef __attribute__((address_space(1))) unsigned int as1_uint;
typedef __attribute__((address_space(3))) unsigned int as3_uint;
__device__ __forceinline__ void glds16(const u16* g, u16* l) {
    // async global->LDS, 16B/lane; LDS dest = wave-uniform base + lane*16
    __builtin_amdgcn_global_load_lds((as1_uint*)(u16*)g, (as3_uint*)l, 16, 0, 0);
}

// ===========================================================================
// Fused fp32->bf16 convert of all 5 inputs (one launch).
// ===========================================================================
__global__ __launch_bounds__(256) void cvt5(const float* __restrict__ x,
                                            const float* __restrict__ wq,
                                            const float* __restrict__ wk,
                                            const float* __restrict__ wv,
                                            const float* __restrict__ wo,
                                            u16* __restrict__ xb,  u16* __restrict__ wqb,
                                            u16* __restrict__ wkb, u16* __restrict__ wvb,
                                            u16* __restrict__ wob) {
    constexpr int E0 = BATCH * T_SEQ * DIMC;          // 8388608
    constexpr int E1 = E0 + DIMC * DIMC;              // +4194304
    constexpr int E2 = E1 + KVDIM * DIMC;             // +1048576
    constexpr int E3 = E2 + KVDIM * DIMC;             // +1048576
    constexpr int E4 = E3 + DIMC * DIMC;              // 18874368 total
    for (int i = (blockIdx.x * 256 + threadIdx.x) * 4; i < E4; i += gridDim.x * 1024) {
        const float* s; u16* d; int off;
        if (i < E0)      { s = x;  d = xb;  off = 0;  }
        else if (i < E1) { s = wq; d = wqb; off = E0; }
        else if (i < E2) { s = wk; d = wkb; off = E1; }
        else if (i < E3) { s = wv; d = wvb; off = E2; }
        else             { s = wo; d = wob; off = E3; }
        f32x4 v = *(const f32x4*)(s + (i - off));
        u16x4 o;
        #pragma unroll
        for (int e = 0; e < 4; ++e) o[e] = f2bf(v[e]);
        *(u16x4*)(d + (i - off)) = o;
    }
}

// ===========================================================================
// GEMM core: C = A[M][K] . W[N][K]^T, bf16 in, global_load_lds staging,
// 128x128 tile, BK=64 as two 32-col LDS panels (row stride stays 32 elems ->
// same bank/chunk behavior as BK=32, half the barriers).
// rope: fused rotary, hardware v_sin/v_cos in revolutions (fract-reduced).
// ===========================================================================
template <bool OUTF32>
__device__ __forceinline__ void gemm_core(const u16* __restrict__ A,
                                          const u16* __restrict__ W,
                                          void* __restrict__ Cv,
                                          int rowBase, int colBase,
                                          int N, int K, bool rope) {
    __shared__ __align__(16) u16 As[2 * 128 * 32];   // panel h at h*4096 elems
    __shared__ __align__(16) u16 Bs[2 * 128 * 32];

    const int tid  = threadIdx.x;
    const int lane = tid & 63;
    const int w    = tid >> 6;
    const int quad = lane >> 4;
    const int ln   = lane & 15;
    const int wm = (w >> 1) * 64;
    const int wn = (w & 1) * 64;

    f32x4 acc[4][4] = {};

    // staging: chunk c = 16 rows x 32 cols; lane i -> row c*16+(i>>2), col (i&3)*8
    const int srow = lane >> 2;
    const int scol = (lane & 3) * 8;
    const u16* aC0 = A + (size_t)(rowBase + w * 16 + srow) * K + scol;
    const u16* aC1 = A + (size_t)(rowBase + (w + 4) * 16 + srow) * K + scol;
    const u16* bC0 = W + (size_t)(colBase + w * 16 + srow) * K + scol;
    const u16* bC1 = W + (size_t)(colBase + (w + 4) * 16 + srow) * K + scol;
    u16* asl0 = As + w * 512;
    u16* asl1 = As + (w + 4) * 512;
    u16* bsl0 = Bs + w * 512;
    u16* bsl1 = Bs + (w + 4) * 512;

    for (int kk = 0; kk < K; kk += 64) {
        __syncthreads();
        glds16(aC0 + kk, asl0);
        glds16(aC1 + kk, asl1);
        glds16(bC0 + kk, bsl0);
        glds16(bC1 + kk, bsl1);
        glds16(aC0 + kk + 32, asl0 + 4096);
        glds16(aC1 + kk + 32, asl1 + 4096);
        glds16(bC0 + kk + 32, bsl0 + 4096);
        glds16(bC1 + kk + 32, bsl1 + 4096);
        __syncthreads();   // vmcnt(0) drain -> both panels visible

        #pragma unroll
        for (int hp = 0; hp < 2; ++hp) {
            const u16* Ap = As + hp * 4096;
            const u16* Bp = Bs + hp * 4096;
            bf16x8 bw[4];
            #pragma unroll
            for (int j = 0; j < 4; ++j)
                bw[j] = *(const bf16x8*)(Bp + (wn + j * 16 + ln) * 32 + quad * 8);
            #pragma unroll
            for (int i = 0; i < 4; ++i) {
                bf16x8 af = *(const bf16x8*)(Ap + (wm + i * 16 + ln) * 32 + quad * 8);
                #pragma unroll
                for (int j = 0; j < 4; ++j)
                    acc[i][j] = __builtin_amdgcn_mfma_f32_16x16x32_bf16(af, bw[j], acc[i][j], 0, 0, 0);
            }
        }
    }

    if (rope) {
        // head-local d = j*16+ln; pairs (d, d+32) -> (acc[i][j], acc[i][j+2]).
        // angle = t * 10000^(-d/32); hw sin/cos take revolutions, fract-reduce.
        #pragma unroll
        for (int j = 0; j < 2; ++j) {
            const int d = j * 16 + ln;
            const float invrev = exp2f(-(float)d * (13.287712379549449f / 32.0f))
                                 * 0.15915494309189535f;   // /2pi
            #pragma unroll
            for (int i = 0; i < 4; ++i) {
                #pragma unroll
                for (int r = 0; r < 4; ++r) {
                    const int t = (rowBase + wm + i * 16 + quad * 4 + r) & (T_SEQ - 1);
                    float rev = (float)t * invrev;
                    float fr = rev - floorf(rev);
                    float sn = __builtin_amdgcn_sinf(fr);
                    float cs = __builtin_amdgcn_cosf(fr);
                    float a0 = acc[i][j][r], a2 = acc[i][j + 2][r];
                    acc[i][j][r]     = a0 * cs - a2 * sn;
                    acc[i][j + 2][r] = a2 * cs + a0 * sn;
                }
            }
        }
    }

    #pragma unroll
    for (int i = 0; i < 4; ++i) {
        int mrow = rowBase + wm + i * 16 + quad * 4;
        #pragma unroll
        for (int j = 0; j < 4; ++j) {
            int n = colBase + wn + j * 16 + ln;
            #pragma unroll
            for (int r = 0; r < 4; ++r) {
                if constexpr (OUTF32)
                    ((float*)Cv)[(size_t)(mrow + r) * N + n] = acc[i][j][r];
                else
                    ((u16*)Cv)[(size_t)(mrow + r) * N + n] = f2bf(acc[i][j][r]);
            }
        }
    }
}

// Fused QKV: grid.x 0..23 -> Q cols (16 blks) | K cols (4) | V cols (4)
__global__ __launch_bounds__(256, 4) void qkv_gemm(const u16* __restrict__ xb,
                                                   const u16* __restrict__ wqb,
                                                   const u16* __restrict__ wkb,
                                                   const u16* __restrict__ wvb,
                                                   u16* __restrict__ Qb,
                                                   u16* __restrict__ Kb,
                                                   u16* __restrict__ Vb) {
    const int nb = blockIdx.x;
    const int rowBase = blockIdx.y * 128;
    const u16* W; u16* C; int colBase, N; bool rope;
    if (nb < 16)      { W = wqb; C = Qb; colBase = nb * 128;        N = DIMC;  rope = true; }
    else if (nb < 20) { W = wkb; C = Kb; colBase = (nb - 16) * 128; N = KVDIM; rope = true; }
    else              { W = wvb; C = Vb; colBase = (nb - 20) * 128; N = KVDIM; rope = false; }
    gemm_core<false>(xb, W, C, rowBase, colBase, N, DIMC, rope);
}

// ===========================================================================
// O-projection GEMM: 128x64 tiles -> grid (32,32) = 1024 blocks = 4/CU.
// 4 waves, each 32 rows x 64 cols (acc 2x4). BK=64 two-panel staging.
// ===========================================================================
__global__ __launch_bounds__(256, 4) void gemm_out64(const u16* __restrict__ A,
                                                     const u16* __restrict__ W,
                                                     float* __restrict__ C) {
    __shared__ __align__(16) u16 As[2 * 128 * 32];   // 16 KB
    __shared__ __align__(16) u16 Bs[2 * 64 * 32];    //  8 KB

    const int tid  = threadIdx.x;
    const int lane = tid & 63;
    const int w    = tid >> 6;
    const int quad = lane >> 4;
    const int ln   = lane & 15;
    const int rowBase = blockIdx.y * 128;
    const int colBase = blockIdx.x * 64;
    const int wm = w * 32;
    constexpr int K = DIMC, N = DIMC;

    f32x4 acc[2][4] = {};

    const int srow = lane >> 2;
    const int scol = (lane & 3) * 8;
    const u16* aC0 = A + (size_t)(rowBase + w * 16 + srow) * K + scol;
    const u16* aC1 = A + (size_t)(rowBase + (w + 4) * 16 + srow) * K + scol;
    const u16* bC  = W + (size_t)(colBase + w * 16 + srow) * K + scol;
    u16* asl0 = As + w * 512;
    u16* asl1 = As + (w + 4) * 512;
    u16* bsl  = Bs + w * 512;

    for (int kk = 0; kk < K; kk += 64) {
        __syncthreads();
        glds16(aC0 + kk, asl0);
        glds16(aC1 + kk, asl1);
        glds16(bC  + kk, bsl);
        glds16(aC0 + kk + 32, asl0 + 4096);
        glds16(aC1 + kk + 32, asl1 + 4096);
        glds16(bC  + kk + 32, bsl + 2048);
        __syncthreads();

        #pragma unroll
        for (int hp = 0; hp < 2; ++hp) {
            const u16* Ap = As + hp * 4096;
            const u16* Bp = Bs + hp * 2048;
            bf16x8 bw[4];
            #pragma unroll
            for (int j = 0; j < 4; ++j)
                bw[j] = *(const bf16x8*)(Bp + (j * 16 + ln) * 32 + quad * 8);
            #pragma unroll
            for (int i = 0; i < 2; ++i) {
                bf16x8 af = *(const bf16x8*)(Ap + (wm + i * 16 + ln) * 32 + quad * 8);
                #pragma unroll
                for (int j = 0; j < 4; ++j)
                    acc[i][j] = __builtin_amdgcn_mfma_f32_16x16x32_bf16(af, bw[j], acc[i][j], 0, 0, 0);
            }
        }
    }

    #pragma unroll
    for (int i = 0; i < 2; ++i) {
        int mrow = rowBase + wm + i * 16 + quad * 4;
        #pragma unroll
        for (int j = 0; j < 4; ++j) {
            int n = colBase + j * 16 + ln;
            #pragma unroll
            for (int r = 0; r < 4; ++r)
                C[(size_t)(mrow + r) * N + n] = acc[i][j][r];
        }
    }
}

// ===========================================================================
// V [B*T][KVDIM] -> Vt [B][KVDIM][T]
// ===========================================================================
__global__ __launch_bounds__(256) void transpose_v(const u16* __restrict__ V,
                                                   u16* __restrict__ Vt) {
    __shared__ __align__(16) u16 tile[32][33];
    const int x = threadIdx.x & 31;
    const int y = threadIdx.x >> 5;
    const int tok0 = blockIdx.y * 32;
    const int c0   = blockIdx.x * 32;
    #pragma unroll
    for (int yy = 0; yy < 32; yy += 8)
        tile[y + yy][x] = V[(size_t)(tok0 + y + yy) * KVDIM + c0 + x];
    __syncthreads();
    const int b  = tok0 >> 11;
    const int t0 = tok0 & (T_SEQ - 1);
    #pragma unroll
    for (int yy = 0; yy < 32; yy += 8)
        Vt[(size_t)(b * KVDIM + c0 + y + yy) * T_SEQ + t0 + x] = tile[x][y + yy];
}

// ===========================================================================
// Flash attention. grid = (16, NH, B), block = 256 (4 waves).
// 64-row Q tiles; block processes qt = blockIdx.x and 31-blockIdx.x
// sequentially -> 33 key-tiles per block, perfectly uniform load.
// R8: swapped QK^T — s[st] = mfma(K_frag, Q_frag) => D[key][q], so each lane
// holds 16 scores for its own q-row (q = ln). With the key->slot permutation
//   slot(k) = 32*(k>>5) + 8*((k>>2)&3) + 4*((k>>4)&1) + (k&3)
// applied to BOTH P columns and V rows, each lane's packed P words are
// exactly its PV A-fragment: no Ps LDS, no cross-lane exchange at all.
// Softmax: fixed shift M0=8, per-lane scalar l partial, epilogue quad-reduce.
// ===========================================================================
__global__ __launch_bounds__(256) void attn(const u16* __restrict__ Q,
                                            const u16* __restrict__ Kx,
                                            const u16* __restrict__ Vt,
                                            u16* __restrict__ O) {
    __shared__ __align__(16) u16 Ks[64][72];       // [key][dim]
    __shared__ __align__(16) u16 Vs[64][72];       // [dim][slot]  (slot-permuted keys)

    const int tid  = threadIdx.x;
    const int lane = tid & 63;
    const int w    = tid >> 6;
    const int quad = lane >> 4;
    const int ln   = lane & 15;
    const int h    = blockIdx.y;
    const int b    = blockIdx.z;
    const int kvh  = h >> 2;

    const int srow = tid >> 2;           // 0..63
    const int c    = tid & 3;
    const int scol = c * 16;             // token group base (16 tokens)
    // V slot base for this lane's 16 tokens: tokens 16c+4m+p -> slot vsb+8m+p
    const int vsb  = 32 * (c >> 1) + 4 * (c & 1);
    const u16* kbase = Kx + (size_t)(b * T_SEQ + srow) * KVDIM + kvh * HDIM + scol;
    const u16* vbase = Vt + (size_t)(b * KVDIM + kvh * HDIM + srow) * T_SEQ;

    const float K1 = 0.125f * 1.4426950408889634f;   // scale * log2(e)
    const float K2 = 8.0f * 1.4426950408889634f;     // M0 * log2(e)

    #pragma unroll
    for (int phase = 0; phase < 2; ++phase) {
        const int qt = phase ? (31 - (int)blockIdx.x) : (int)blockIdx.x;
        const int qr0 = qt * 64 + w * 16;

        const u16* qp = Q + (size_t)(b * T_SEQ + qr0 + ln) * DIMC + h * HDIM + quad * 8;
        const bf16x8 bq0 = *(const bf16x8*)qp;        // B-operand: col = q = ln
        const bf16x8 bq1 = *(const bf16x8*)(qp + 32);

        f32x4 o[4] = {};
        float lsum = 0.0f;

        for (int kt = 0; kt <= qt; ++kt) {
            const int k0 = kt * 64;
            __syncthreads();
            *(bf16x8*)&Ks[srow][scol]     = *(const bf16x8*)(kbase + (size_t)k0 * KVDIM);
            *(bf16x8*)&Ks[srow][scol + 8] = *(const bf16x8*)(kbase + (size_t)k0 * KVDIM + 8);
            {   // V staging, slot-permuted: 4x ds_write_b64
                union { bf16x8 v; u16x4 h4[2]; } va, vb;
                va.v = *(const bf16x8*)(vbase + k0 + scol);
                vb.v = *(const bf16x8*)(vbase + k0 + scol + 8);
                *(u16x4*)&Vs[srow][vsb]      = va.h4[0];   // tokens 16c+0..3
                *(u16x4*)&Vs[srow][vsb + 8]  = va.h4[1];   // tokens 16c+4..7
                *(u16x4*)&Vs[srow][vsb + 16] = vb.h4[0];   // tokens 16c+8..11
                *(u16x4*)&Vs[srow][vsb + 24] = vb.h4[1];   // tokens 16c+12..15
            }
            __syncthreads();

            // QK^T swapped: D[key][q]; lane holds keys st*16+quad*4+r for q=ln
            f32x4 s[4];
            #pragma unroll
            for (int st = 0; st < 4; ++st) {
                f32x4 z = {};
                s[st] = __builtin_amdgcn_mfma_f32_16x16x32_bf16(
                            *(const bf16x8*)&Ks[st * 16 + ln][quad * 8], bq0, z, 0, 0, 0);
                s[st] = __builtin_amdgcn_mfma_f32_16x16x32_bf16(
                            *(const bf16x8*)&Ks[st * 16 + ln][32 + quad * 8], bq1, s[st], 0, 0, 0);
            }

            // softmax numerator + in-register pack. pk[2st+rp] = keys
            // (16st+4quad+2rp, +1) = slots (32(st>>1)+8quad+4(st&1)+2rp, +1)
            unsigned int pk[8];
            if (kt != qt) {
                #pragma unroll
                for (int st = 0; st < 4; ++st) {
                    float e0 = exp2f(fmaf(s[st][0], K1, -K2));
                    float e1 = exp2f(fmaf(s[st][1], K1, -K2));
                    float e2 = exp2f(fmaf(s[st][2], K1, -K2));
                    float e3 = exp2f(fmaf(s[st][3], K1, -K2));
                    lsum += (e0 + e1) + (e2 + e3);
                    pk[2 * st]     = pack2_bf16(e0, e1);
                    pk[2 * st + 1] = pack2_bf16(e2, e3);
                }
            } else {
                const int thr = w * 16 + ln;            // q local in 64-block
                #pragma unroll
                for (int st = 0; st < 4; ++st) {
                    float e[4];
                    #pragma unroll
                    for (int r = 0; r < 4; ++r) {
                        const int key = st * 16 + quad * 4 + r;
                        e[r] = (key > thr) ? 0.0f : exp2f(fmaf(s[st][r], K1, -K2));
                    }
                    lsum += (e[0] + e[1]) + (e[2] + e[3]);
                    pk[2 * st]     = pack2_bf16(e[0], e[1]);
                    pk[2 * st + 1] = pack2_bf16(e[2], e[3]);
                }
            }

            // lane's own packed words are its A-fragment (slots 8*quad..+7 and
            // 32+8*quad..+7): pa0 = {pk[0..3]} (st 0,1), pa1 = {pk[4..7]} (st 2,3)
            union { unsigned int u[4]; bf16x8 v; } a0, a1;
            a0.u[0] = pk[0]; a0.u[1] = pk[1]; a0.u[2] = pk[2]; a0.u[3] = pk[3];
            a1.u[0] = pk[4]; a1.u[1] = pk[5]; a1.u[2] = pk[6]; a1.u[3] = pk[7];

            #pragma unroll
            for (int t = 0; t < 4; ++t) {
                o[t] = __builtin_amdgcn_mfma_f32_16x16x32_bf16(
                           a0.v, *(const bf16x8*)&Vs[t * 16 + ln][quad * 8], o[t], 0, 0, 0);
                o[t] = __builtin_amdgcn_mfma_f32_16x16x32_bf16(
                           a1.v, *(const bf16x8*)&Vs[t * 16 + ln][32 + quad * 8], o[t], 0, 0, 0);
            }
        }

        // lsum is per-lane (q = ln, 16 keys/tile): reduce across quads, then
        // redistribute to the O layout (q = quad*4+r held at col ln).
        float ls = lsum;
        ls += __shfl_xor(ls, 16);
        ls += __shfl_xor(ls, 32);   // all lanes with same ln now hold total(q=ln)
        #pragma unroll
        for (int r = 0; r < 4; ++r) {
            const float inv = 1.0f / __shfl(ls, quad * 4 + r);
            size_t obase = (size_t)(b * T_SEQ + qr0 + quad * 4 + r) * DIMC + h * HDIM;
            #pragma unroll
            for (int t = 0; t < 4; ++t)
                O[obase + t * 16 + ln] = f2bf(o[t][r] * inv);
        }
    }
}

// ===========================================================================
extern "C" void kernel_launch(void* const* d_in, const int* in_sizes, int n_in,
                              void* d_out, int out_size, void* d_ws, size_t ws_size,
                              hipStream_t stream) {
    const float* x  = (const float*)d_in[0];
    const float* wq = (const float*)d_in[1];
    const float* wk = (const float*)d_in[2];
    const float* wv = (const float*)d_in[3];
    const float* wo = (const float*)d_in[4];
    float* out = (float*)d_out;

    char* ws = (char*)d_ws;
    constexpr size_t MB = 1024 * 1024;
    u16* Qb  = (u16*)(ws);             // 16 MB [4096][2048]
    u16* Kb  = (u16*)(ws + 16 * MB);   //  4 MB [4096][512]
    u16* Vb  = (u16*)(ws + 20 * MB);   //  4 MB [4096][512]
    u16* Vtb = (u16*)(ws + 24 * MB);   //  4 MB [2][512][2048]
    u16* AOb = (u16*)(ws + 28 * MB);   // 16 MB [4096][2048]  (aliases xb)
    u16* xb  = AOb;                    // x dead before attn writes AOb
    u16* wqb = (u16*)(ws + 44 * MB);   //  8 MB
    u16* wkb = (u16*)(ws + 52 * MB);   //  2 MB
    u16* wvb = (u16*)(ws + 54 * MB);   //  2 MB
    u16* wob = (u16*)(ws + 56 * MB);   //  8 MB
    const int M = BATCH * T_SEQ;       // 4096

    hipLaunchKernelGGL(cvt5, dim3(2048), dim3(256), 0, stream,
                       x, wq, wk, wv, wo, xb, wqb, wkb, wvb, wob);
    hipLaunchKernelGGL(qkv_gemm, dim3(24, M / 128), dim3(256), 0, stream,
                       xb, wqb, wkb, wvb, Qb, Kb, Vb);
    hipLaunchKernelGGL(transpose_v, dim3(KVDIM / 32, M / 32), dim3(256), 0, stream, Vb, Vtb);
    hipLaunchKernelGGL(attn, dim3(16, NHEAD, BATCH), dim3(256), 0, stream,
                       Qb, Kb, Vtb, AOb);
    hipLaunchKernelGGL(gemm_out64, dim3(DIMC / 64, M / 128), dim3(256), 0, stream,
                       AOb, wob, out);
}

// Round 2
// 304.507 us; speedup vs baseline: 1.0498x; 1.0401x over previous
//
#include <hip/hip_runtime.h>

// Attention_6219112645023 — fp32 in / fp32 out, bf16 internal compute (MFMA).
// B=2, T=2048, DIM=2048, NH=32, NKV=8, HD=64. Causal GQA + RoPE + projections.
// Pipeline: cvt5 -> fused QKV gemm -> transpose(V) -> flash attn -> O gemm.
// R7: BK=64 (two 32-col LDS panels, barriers halved), hw-sin/cos RoPE,
// O-projection as 128x64-tile gemm_out64 (1024 blocks = 4/CU).
// R8: attn — swapped QK^T (mfma(K,Q)) + key-slot permutation makes each
// lane's packed P words its own PV A-fragment: Ps LDS eliminated entirely.
// R9: attn — T14 async-STAGE pipeline: tile kt+1 global loads issued into
// registers under tile kt's compute (vmcnt wait lands at next ds_write);
// second barrier is lgkmcnt(0) + raw s_barrier (no vmcnt drain, prefetch
// stays in flight). s_setprio(1) around QK/PV MFMA clusters (T5).

typedef unsigned short u16;
typedef __attribute__((ext_vector_type(8))) short bf16x8;  // 8 bf16 in 4 VGPRs
typedef __attribute__((ext_vector_type(4))) float f32x4;
typedef __attribute__((ext_vector_type(4))) unsigned short u16x4;

constexpr int T_SEQ = 2048;
constexpr int DIMC  = 2048;
constexpr int NHEAD = 32;
constexpr int HDIM  = 64;
constexpr int KVDIM = 512;   // NKV * HDIM
constexpr int BATCH = 2;

__device__ __forceinline__ u16 f2bf(float f) {
    union { float f; unsigned int i; } v; v.f = f;
    unsigned int r = v.i + 0x7FFFu + ((v.i >> 16) & 1u);   // RNE
    return (u16)(r >> 16);
}

// pack two f32 -> (bf16 lo = e0, bf16 hi = e1), truncating (P in [0,1]).
__device__ __forceinline__ unsigned int pack2_bf16(float e0, float e1) {
    return __builtin_amdgcn_perm(__float_as_uint(e1), __float_as_uint(e0),
                                 0x07060302u);
}

typedef __attribute__((address_space(1))) unsigned int as1_uint;
typedef __attribute__((address_space(3))) unsigned int as3_uint;
__device__ __forceinline__ void glds16(const u16* g, u16* l) {
    // async global->LDS, 16B/lane; LDS dest = wave-uniform base + lane*16
    __builtin_amdgcn_global_load_lds((as1_uint*)(u16*)g, (as3_uint*)l, 16, 0, 0);
}

// ===========================================================================
// Fused fp32->bf16 convert of all 5 inputs (one launch).
// ===========================================================================
__global__ __launch_bounds__(256) void cvt5(const float* __restrict__ x,
                                            const float* __restrict__ wq,
                                            const float* __restrict__ wk,
                                            const float* __restrict__ wv,
                                            const float* __restrict__ wo,
                                            u16* __restrict__ xb,  u16* __restrict__ wqb,
                                            u16* __restrict__ wkb, u16* __restrict__ wvb,
                                            u16* __restrict__ wob) {
    constexpr int E0 = BATCH * T_SEQ * DIMC;          // 8388608
    constexpr int E1 = E0 + DIMC * DIMC;              // +4194304
    constexpr int E2 = E1 + KVDIM * DIMC;             // +1048576
    constexpr int E3 = E2 + KVDIM * DIMC;             // +1048576
    constexpr int E4 = E3 + DIMC * DIMC;              // 18874368 total
    for (int i = (blockIdx.x * 256 + threadIdx.x) * 4; i < E4; i += gridDim.x * 1024) {
        const float* s; u16* d; int off;
        if (i < E0)      { s = x;  d = xb;  off = 0;  }
        else if (i < E1) { s = wq; d = wqb; off = E0; }
        else if (i < E2) { s = wk; d = wkb; off = E1; }
        else if (i < E3) { s = wv; d = wvb; off = E2; }
        else             { s = wo; d = wob; off = E3; }
        f32x4 v = *(const f32x4*)(s + (i - off));
        u16x4 o;
        #pragma unroll
        for (int e = 0; e < 4; ++e) o[e] = f2bf(v[e]);
        *(u16x4*)(d + (i - off)) = o;
    }
}

// ===========================================================================
// GEMM core: C = A[M][K] . W[N][K]^T, bf16 in, global_load_lds staging,
// 128x128 tile, BK=64 as two 32-col LDS panels.
// ===========================================================================
template <bool OUTF32>
__device__ __forceinline__ void gemm_core(const u16* __restrict__ A,
                                          const u16* __restrict__ W,
                                          void* __restrict__ Cv,
                                          int rowBase, int colBase,
                                          int N, int K, bool rope) {
    __shared__ __align__(16) u16 As[2 * 128 * 32];   // panel h at h*4096 elems
    __shared__ __align__(16) u16 Bs[2 * 128 * 32];

    const int tid  = threadIdx.x;
    const int lane = tid & 63;
    const int w    = tid >> 6;
    const int quad = lane >> 4;
    const int ln   = lane & 15;
    const int wm = (w >> 1) * 64;
    const int wn = (w & 1) * 64;

    f32x4 acc[4][4] = {};

    const int srow = lane >> 2;
    const int scol = (lane & 3) * 8;
    const u16* aC0 = A + (size_t)(rowBase + w * 16 + srow) * K + scol;
    const u16* aC1 = A + (size_t)(rowBase + (w + 4) * 16 + srow) * K + scol;
    const u16* bC0 = W + (size_t)(colBase + w * 16 + srow) * K + scol;
    const u16* bC1 = W + (size_t)(colBase + (w + 4) * 16 + srow) * K + scol;
    u16* asl0 = As + w * 512;
    u16* asl1 = As + (w + 4) * 512;
    u16* bsl0 = Bs + w * 512;
    u16* bsl1 = Bs + (w + 4) * 512;

    for (int kk = 0; kk < K; kk += 64) {
        __syncthreads();
        glds16(aC0 + kk, asl0);
        glds16(aC1 + kk, asl1);
        glds16(bC0 + kk, bsl0);
        glds16(bC1 + kk, bsl1);
        glds16(aC0 + kk + 32, asl0 + 4096);
        glds16(aC1 + kk + 32, asl1 + 4096);
        glds16(bC0 + kk + 32, bsl0 + 4096);
        glds16(bC1 + kk + 32, bsl1 + 4096);
        __syncthreads();   // vmcnt(0) drain -> both panels visible

        #pragma unroll
        for (int hp = 0; hp < 2; ++hp) {
            const u16* Ap = As + hp * 4096;
            const u16* Bp = Bs + hp * 4096;
            bf16x8 bw[4];
            #pragma unroll
            for (int j = 0; j < 4; ++j)
                bw[j] = *(const bf16x8*)(Bp + (wn + j * 16 + ln) * 32 + quad * 8);
            #pragma unroll
            for (int i = 0; i < 4; ++i) {
                bf16x8 af = *(const bf16x8*)(Ap + (wm + i * 16 + ln) * 32 + quad * 8);
                #pragma unroll
                for (int j = 0; j < 4; ++j)
                    acc[i][j] = __builtin_amdgcn_mfma_f32_16x16x32_bf16(af, bw[j], acc[i][j], 0, 0, 0);
            }
        }
    }

    if (rope) {
        #pragma unroll
        for (int j = 0; j < 2; ++j) {
            const int d = j * 16 + ln;
            const float invrev = exp2f(-(float)d * (13.287712379549449f / 32.0f))
                                 * 0.15915494309189535f;   // /2pi
            #pragma unroll
            for (int i = 0; i < 4; ++i) {
                #pragma unroll
                for (int r = 0; r < 4; ++r) {
                    const int t = (rowBase + wm + i * 16 + quad * 4 + r) & (T_SEQ - 1);
                    float rev = (float)t * invrev;
                    float fr = rev - floorf(rev);
                    float sn = __builtin_amdgcn_sinf(fr);
                    float cs = __builtin_amdgcn_cosf(fr);
                    float a0 = acc[i][j][r], a2 = acc[i][j + 2][r];
                    acc[i][j][r]     = a0 * cs - a2 * sn;
                    acc[i][j + 2][r] = a2 * cs + a0 * sn;
                }
            }
        }
    }

    #pragma unroll
    for (int i = 0; i < 4; ++i) {
        int mrow = rowBase + wm + i * 16 + quad * 4;
        #pragma unroll
        for (int j = 0; j < 4; ++j) {
            int n = colBase + wn + j * 16 + ln;
            #pragma unroll
            for (int r = 0; r < 4; ++r) {
                if constexpr (OUTF32)
                    ((float*)Cv)[(size_t)(mrow + r) * N + n] = acc[i][j][r];
                else
                    ((u16*)Cv)[(size_t)(mrow + r) * N + n] = f2bf(acc[i][j][r]);
            }
        }
    }
}

// Fused QKV: grid.x 0..23 -> Q cols (16 blks) | K cols (4) | V cols (4)
__global__ __launch_bounds__(256, 4) void qkv_gemm(const u16* __restrict__ xb,
                                                   const u16* __restrict__ wqb,
                                                   const u16* __restrict__ wkb,
                                                   const u16* __restrict__ wvb,
                                                   u16* __restrict__ Qb,
                                                   u16* __restrict__ Kb,
                                                   u16* __restrict__ Vb) {
    const int nb = blockIdx.x;
    const int rowBase = blockIdx.y * 128;
    const u16* W; u16* C; int colBase, N; bool rope;
    if (nb < 16)      { W = wqb; C = Qb; colBase = nb * 128;        N = DIMC;  rope = true; }
    else if (nb < 20) { W = wkb; C = Kb; colBase = (nb - 16) * 128; N = KVDIM; rope = true; }
    else              { W = wvb; C = Vb; colBase = (nb - 20) * 128; N = KVDIM; rope = false; }
    gemm_core<false>(xb, W, C, rowBase, colBase, N, DIMC, rope);
}

// ===========================================================================
// O-projection GEMM: 128x64 tiles -> grid (32,32) = 1024 blocks = 4/CU.
// ===========================================================================
__global__ __launch_bounds__(256, 4) void gemm_out64(const u16* __restrict__ A,
                                                     const u16* __restrict__ W,
                                                     float* __restrict__ C) {
    __shared__ __align__(16) u16 As[2 * 128 * 32];   // 16 KB
    __shared__ __align__(16) u16 Bs[2 * 64 * 32];    //  8 KB

    const int tid  = threadIdx.x;
    const int lane = tid & 63;
    const int w    = tid >> 6;
    const int quad = lane >> 4;
    const int ln   = lane & 15;
    const int rowBase = blockIdx.y * 128;
    const int colBase = blockIdx.x * 64;
    const int wm = w * 32;
    constexpr int K = DIMC, N = DIMC;

    f32x4 acc[2][4] = {};

    const int srow = lane >> 2;
    const int scol = (lane & 3) * 8;
    const u16* aC0 = A + (size_t)(rowBase + w * 16 + srow) * K + scol;
    const u16* aC1 = A + (size_t)(rowBase + (w + 4) * 16 + srow) * K + scol;
    const u16* bC  = W + (size_t)(colBase + w * 16 + srow) * K + scol;
    u16* asl0 = As + w * 512;
    u16* asl1 = As + (w + 4) * 512;
    u16* bsl  = Bs + w * 512;

    for (int kk = 0; kk < K; kk += 64) {
        __syncthreads();
        glds16(aC0 + kk, asl0);
        glds16(aC1 + kk, asl1);
        glds16(bC  + kk, bsl);
        glds16(aC0 + kk + 32, asl0 + 4096);
        glds16(aC1 + kk + 32, asl1 + 4096);
        glds16(bC  + kk + 32, bsl + 2048);
        __syncthreads();

        #pragma unroll
        for (int hp = 0; hp < 2; ++hp) {
            const u16* Ap = As + hp * 4096;
            const u16* Bp = Bs + hp * 2048;
            bf16x8 bw[4];
            #pragma unroll
            for (int j = 0; j < 4; ++j)
                bw[j] = *(const bf16x8*)(Bp + (j * 16 + ln) * 32 + quad * 8);
            #pragma unroll
            for (int i = 0; i < 2; ++i) {
                bf16x8 af = *(const bf16x8*)(Ap + (wm + i * 16 + ln) * 32 + quad * 8);
                #pragma unroll
                for (int j = 0; j < 4; ++j)
                    acc[i][j] = __builtin_amdgcn_mfma_f32_16x16x32_bf16(af, bw[j], acc[i][j], 0, 0, 0);
            }
        }
    }

    #pragma unroll
    for (int i = 0; i < 2; ++i) {
        int mrow = rowBase + wm + i * 16 + quad * 4;
        #pragma unroll
        for (int j = 0; j < 4; ++j) {
            int n = colBase + j * 16 + ln;
            #pragma unroll
            for (int r = 0; r < 4; ++r)
                C[(size_t)(mrow + r) * N + n] = acc[i][j][r];
        }
    }
}

// ===========================================================================
// V [B*T][KVDIM] -> Vt [B][KVDIM][T]
// ===========================================================================
__global__ __launch_bounds__(256) void transpose_v(const u16* __restrict__ V,
                                                   u16* __restrict__ Vt) {
    __shared__ __align__(16) u16 tile[32][33];
    const int x = threadIdx.x & 31;
    const int y = threadIdx.x >> 5;
    const int tok0 = blockIdx.y * 32;
    const int c0   = blockIdx.x * 32;
    #pragma unroll
    for (int yy = 0; yy < 32; yy += 8)
        tile[y + yy][x] = V[(size_t)(tok0 + y + yy) * KVDIM + c0 + x];
    __syncthreads();
    const int b  = tok0 >> 11;
    const int t0 = tok0 & (T_SEQ - 1);
    #pragma unroll
    for (int yy = 0; yy < 32; yy += 8)
        Vt[(size_t)(b * KVDIM + c0 + y + yy) * T_SEQ + t0 + x] = tile[x][y + yy];
}

// ===========================================================================
// Flash attention. grid = (16, NH, B), block = 256 (4 waves).
// 64-row Q tiles; block processes qt = blockIdx.x and 31-blockIdx.x
// sequentially -> 33 key-tiles per block, perfectly uniform load.
// R8: swapped QK^T (D[key][q]) + key->slot permutation
//   slot(k) = 32*(k>>5) + 8*((k>>2)&3) + 4*((k>>4)&1) + (k&3)
// makes each lane's packed P words its own PV A-fragment (no P exchange).
// R9: T14 async-STAGE pipeline per kt:
//   syncthreads (drains vmcnt: tile-kt regs ready, prior readers done)
//   ds_write K/V tile kt from regs
//   issue global loads tile kt+1 -> regs (fly under compute)
//   lgkmcnt(0) + raw s_barrier (NO vmcnt drain -> prefetch stays in flight)
//   compute kt (setprio(1) around MFMA clusters)
// ===========================================================================
__global__ __launch_bounds__(256) void attn(const u16* __restrict__ Q,
                                            const u16* __restrict__ Kx,
                                            const u16* __restrict__ Vt,
                                            u16* __restrict__ O) {
    __shared__ __align__(16) u16 Ks[64][72];       // [key][dim]
    __shared__ __align__(16) u16 Vs[64][72];       // [dim][slot]  (slot-permuted keys)

    const int tid  = threadIdx.x;
    const int lane = tid & 63;
    const int w    = tid >> 6;
    const int quad = lane >> 4;
    const int ln   = lane & 15;
    const int h    = blockIdx.y;
    const int b    = blockIdx.z;
    const int kvh  = h >> 2;

    const int srow = tid >> 2;           // 0..63
    const int c    = tid & 3;
    const int scol = c * 16;             // token group base (16 tokens)
    const int vsb  = 32 * (c >> 1) + 4 * (c & 1);
    const u16* kbase = Kx + (size_t)(b * T_SEQ + srow) * KVDIM + kvh * HDIM + scol;
    const u16* vbase = Vt + (size_t)(b * KVDIM + kvh * HDIM + srow) * T_SEQ;

    const float K1 = 0.125f * 1.4426950408889634f;   // scale * log2(e)
    const float K2 = 8.0f * 1.4426950408889634f;     // M0 * log2(e)

    #pragma unroll
    for (int phase = 0; phase < 2; ++phase) {
        const int qt = phase ? (31 - (int)blockIdx.x) : (int)blockIdx.x;
        const int qr0 = qt * 64 + w * 16;

        const u16* qp = Q + (size_t)(b * T_SEQ + qr0 + ln) * DIMC + h * HDIM + quad * 8;
        const bf16x8 bq0 = *(const bf16x8*)qp;        // B-operand: col = q = ln
        const bf16x8 bq1 = *(const bf16x8*)(qp + 32);

        f32x4 o[4] = {};
        float lsum = 0.0f;

        // pipeline prologue: issue tile-0 staging loads into registers
        bf16x8 kra = *(const bf16x8*)kbase;
        bf16x8 krb = *(const bf16x8*)(kbase + 8);
        bf16x8 vra = *(const bf16x8*)(vbase + scol);
        bf16x8 vrb = *(const bf16x8*)(vbase + scol + 8);

        for (int kt = 0; kt <= qt; ++kt) {
            // full barrier: drains vmcnt (staged regs for tile kt ready) and
            // guarantees all waves finished reading Ks/Vs of the prior tile.
            __syncthreads();

            *(bf16x8*)&Ks[srow][scol]     = kra;
            *(bf16x8*)&Ks[srow][scol + 8] = krb;
            {   // V staging, slot-permuted: 4x ds_write_b64
                union { bf16x8 v; u16x4 h4[2]; } ua, ub;
                ua.v = vra; ub.v = vrb;
                *(u16x4*)&Vs[srow][vsb]      = ua.h4[0];   // tokens 16c+0..3
                *(u16x4*)&Vs[srow][vsb + 8]  = ua.h4[1];   // tokens 16c+4..7
                *(u16x4*)&Vs[srow][vsb + 16] = ub.h4[0];   // tokens 16c+8..11
                *(u16x4*)&Vs[srow][vsb + 24] = ub.h4[1];   // tokens 16c+12..15
            }

            // prefetch tile kt+1 into regs — flies under this tile's compute
            if (kt < qt) {
                const size_t ko = (size_t)(kt + 1) * 64;
                kra = *(const bf16x8*)(kbase + ko * KVDIM);
                krb = *(const bf16x8*)(kbase + ko * KVDIM + 8);
                vra = *(const bf16x8*)(vbase + ko + scol);
                vrb = *(const bf16x8*)(vbase + ko + scol + 8);
            }

            // own LDS writes drained, then raw barrier (no vmcnt drain!)
            __asm__ __volatile__("s_waitcnt lgkmcnt(0)" ::: "memory");
            __builtin_amdgcn_s_barrier();

            // QK^T swapped: D[key][q]; lane holds keys st*16+quad*4+r for q=ln
            f32x4 s[4];
            __builtin_amdgcn_s_setprio(1);
            #pragma unroll
            for (int st = 0; st < 4; ++st) {
                f32x4 z = {};
                s[st] = __builtin_amdgcn_mfma_f32_16x16x32_bf16(
                            *(const bf16x8*)&Ks[st * 16 + ln][quad * 8], bq0, z, 0, 0, 0);
                s[st] = __builtin_amdgcn_mfma_f32_16x16x32_bf16(
                            *(const bf16x8*)&Ks[st * 16 + ln][32 + quad * 8], bq1, s[st], 0, 0, 0);
            }
            __builtin_amdgcn_s_setprio(0);

            // softmax numerator + in-register pack
            unsigned int pk[8];
            if (kt != qt) {
                #pragma unroll
                for (int st = 0; st < 4; ++st) {
                    float e0 = exp2f(fmaf(s[st][0], K1, -K2));
                    float e1 = exp2f(fmaf(s[st][1], K1, -K2));
                    float e2 = exp2f(fmaf(s[st][2], K1, -K2));
                    float e3 = exp2f(fmaf(s[st][3], K1, -K2));
                    lsum += (e0 + e1) + (e2 + e3);
                    pk[2 * st]     = pack2_bf16(e0, e1);
                    pk[2 * st + 1] = pack2_bf16(e2, e3);
                }
            } else {
                const int thr = w * 16 + ln;            // q local in 64-block
                #pragma unroll
                for (int st = 0; st < 4; ++st) {
                    float e[4];
                    #pragma unroll
                    for (int r = 0; r < 4; ++r) {
                        const int key = st * 16 + quad * 4 + r;
                        e[r] = (key > thr) ? 0.0f : exp2f(fmaf(s[st][r], K1, -K2));
                    }
                    lsum += (e[0] + e[1]) + (e[2] + e[3]);
                    pk[2 * st]     = pack2_bf16(e[0], e[1]);
                    pk[2 * st + 1] = pack2_bf16(e[2], e[3]);
                }
            }

            // lane's packed words are its PV A-fragment
            union { unsigned int u[4]; bf16x8 v; } a0, a1;
            a0.u[0] = pk[0]; a0.u[1] = pk[1]; a0.u[2] = pk[2]; a0.u[3] = pk[3];
            a1.u[0] = pk[4]; a1.u[1] = pk[5]; a1.u[2] = pk[6]; a1.u[3] = pk[7];

            __builtin_amdgcn_s_setprio(1);
            #pragma unroll
            for (int t = 0; t < 4; ++t) {
                o[t] = __builtin_amdgcn_mfma_f32_16x16x32_bf16(
                           a0.v, *(const bf16x8*)&Vs[t * 16 + ln][quad * 8], o[t], 0, 0, 0);
                o[t] = __builtin_amdgcn_mfma_f32_16x16x32_bf16(
                           a1.v, *(const bf16x8*)&Vs[t * 16 + ln][32 + quad * 8], o[t], 0, 0, 0);
            }
            __builtin_amdgcn_s_setprio(0);
        }

        // lsum is per-lane (q = ln): reduce across quads, redistribute to
        // the O layout (q = quad*4+r held at col ln).
        float ls = lsum;
        ls += __shfl_xor(ls, 16);
        ls += __shfl_xor(ls, 32);   // all lanes with same ln hold total(q=ln)
        #pragma unroll
        for (int r = 0; r < 4; ++r) {
            const float inv = 1.0f / __shfl(ls, quad * 4 + r);
            size_t obase = (size_t)(b * T_SEQ + qr0 + quad * 4 + r) * DIMC + h * HDIM;
            #pragma unroll
            for (int t = 0; t < 4; ++t)
                O[obase + t * 16 + ln] = f2bf(o[t][r] * inv);
        }
    }
}

// ===========================================================================
extern "C" void kernel_launch(void* const* d_in, const int* in_sizes, int n_in,
                              void* d_out, int out_size, void* d_ws, size_t ws_size,
                              hipStream_t stream) {
    const float* x  = (const float*)d_in[0];
    const float* wq = (const float*)d_in[1];
    const float* wk = (const float*)d_in[2];
    const float* wv = (const float*)d_in[3];
    const float* wo = (const float*)d_in[4];
    float* out = (float*)d_out;

    char* ws = (char*)d_ws;
    constexpr size_t MB = 1024 * 1024;
    u16* Qb  = (u16*)(ws);             // 16 MB [4096][2048]
    u16* Kb  = (u16*)(ws + 16 * MB);   //  4 MB [4096][512]
    u16* Vb  = (u16*)(ws + 20 * MB);   //  4 MB [4096][512]
    u16* Vtb = (u16*)(ws + 24 * MB);   //  4 MB [2][512][2048]
    u16* AOb = (u16*)(ws + 28 * MB);   // 16 MB [4096][2048]  (aliases xb)
    u16* xb  = AOb;                    // x dead before attn writes AOb
    u16* wqb = (u16*)(ws + 44 * MB);   //  8 MB
    u16* wkb = (u16*)(ws + 52 * MB);   //  2 MB
    u16* wvb = (u16*)(ws + 54 * MB);   //  2 MB
    u16* wob = (u16*)(ws + 56 * MB);   //  8 MB
    const int M = BATCH * T_SEQ;       // 4096

    hipLaunchKernelGGL(cvt5, dim3(2048), dim3(256), 0, stream,
                       x, wq, wk, wv, wo, xb, wqb, wkb, wvb, wob);
    hipLaunchKernelGGL(qkv_gemm, dim3(24, M / 128), dim3(256), 0, stream,
                       xb, wqb, wkb, wvb, Qb, Kb, Vb);
    hipLaunchKernelGGL(transpose_v, dim3(KVDIM / 32, M / 32), dim3(256), 0, stream, Vb, Vtb);
    hipLaunchKernelGGL(attn, dim3(16, NHEAD, BATCH), dim3(256), 0, stream,
                       Qb, Kb, Vtb, AOb);
    hipLaunchKernelGGL(gemm_out64, dim3(DIMC / 64, M / 128), dim3(256), 0, stream,
                       AOb, wob, out);
}

// Round 3
// 298.530 us; speedup vs baseline: 1.0708x; 1.0200x over previous
//
#include <hip/hip_runtime.h>

// Attention_6219112645023 — fp32 in / fp32 out, bf16 internal compute (MFMA).
// B=2, T=2048, DIM=2048, NH=32, NKV=8, HD=64. Causal GQA + RoPE + projections.
// Pipeline: cvt5 -> qkv_gemm8 -> transpose(V) -> flash attn -> O gemm.
// R8: attn — swapped QK^T + key-slot permutation, P stays in registers.
// R9: attn — T14 async-STAGE pipeline + raw s_barrier (no vmcnt drain) + T5.
// R10: qkv projection rewritten as 256x256-tile / BK=64 / 8-wave deep-pipe
// GEMM (m201-style): 128 KiB dbuf LDS, XOR-swizzled LDS reads (conflict-free
// ds_read_b128) with inverse-swizzled glds SOURCE (linear dest, rule #21),
// ONE barrier per K-tile, counted-own-vmcnt, next-tile glds issued under
// current tile's MFMAs, setprio around MFMA clusters, bijective XCD swizzle.

typedef unsigned short u16;
typedef __attribute__((ext_vector_type(8))) short bf16x8;  // 8 bf16 in 4 VGPRs
typedef __attribute__((ext_vector_type(4))) float f32x4;
typedef __attribute__((ext_vector_type(4))) unsigned short u16x4;

constexpr int T_SEQ = 2048;
constexpr int DIMC  = 2048;
constexpr int NHEAD = 32;
constexpr int HDIM  = 64;
constexpr int KVDIM = 512;   // NKV * HDIM
constexpr int BATCH = 2;

__device__ __forceinline__ u16 f2bf(float f) {
    union { float f; unsigned int i; } v; v.f = f;
    unsigned int r = v.i + 0x7FFFu + ((v.i >> 16) & 1u);   // RNE
    return (u16)(r >> 16);
}

// pack two f32 -> (bf16 lo = e0, bf16 hi = e1), truncating (P in [0,1]).
__device__ __forceinline__ unsigned int pack2_bf16(float e0, float e1) {
    return __builtin_amdgcn_perm(__float_as_uint(e1), __float_as_uint(e0),
                                 0x07060302u);
}

typedef __attribute__((address_space(1))) unsigned int as1_uint;
typedef __attribute__((address_space(3))) unsigned int as3_uint;
__device__ __forceinline__ void glds16(const u16* g, u16* l) {
    // async global->LDS, 16B/lane; LDS dest = wave-uniform base + lane*16
    __builtin_amdgcn_global_load_lds((as1_uint*)(u16*)g, (as3_uint*)l, 16, 0, 0);
}

// ===========================================================================
// Fused fp32->bf16 convert of all 5 inputs (one launch).
// ===========================================================================
__global__ __launch_bounds__(256) void cvt5(const float* __restrict__ x,
                                            const float* __restrict__ wq,
                                            const float* __restrict__ wk,
                                            const float* __restrict__ wv,
                                            const float* __restrict__ wo,
                                            u16* __restrict__ xb,  u16* __restrict__ wqb,
                                            u16* __restrict__ wkb, u16* __restrict__ wvb,
                                            u16* __restrict__ wob) {
    constexpr int E0 = BATCH * T_SEQ * DIMC;          // 8388608
    constexpr int E1 = E0 + DIMC * DIMC;              // +4194304
    constexpr int E2 = E1 + KVDIM * DIMC;             // +1048576
    constexpr int E3 = E2 + KVDIM * DIMC;             // +1048576
    constexpr int E4 = E3 + DIMC * DIMC;              // 18874368 total
    for (int i = (blockIdx.x * 256 + threadIdx.x) * 4; i < E4; i += gridDim.x * 1024) {
        const float* s; u16* d; int off;
        if (i < E0)      { s = x;  d = xb;  off = 0;  }
        else if (i < E1) { s = wq; d = wqb; off = E0; }
        else if (i < E2) { s = wk; d = wkb; off = E1; }
        else if (i < E3) { s = wv; d = wvb; off = E2; }
        else             { s = wo; d = wob; off = E3; }
        f32x4 v = *(const f32x4*)(s + (i - off));
        u16x4 o;
        #pragma unroll
        for (int e = 0; e < 4; ++e) o[e] = f2bf(v[e]);
        *(u16x4*)(d + (i - off)) = o;
    }
}

// ===========================================================================
// QKV projection, 256x256 tile, BK=64, 512 threads (8 waves, 2M x 4N).
// C = A[4096][2048] . W[N][2048]^T.  Per-wave output 128x64 = acc[8][4].
// LDS: double-buffered A-tile + B-tile (256x64 bf16 each) = 128 KiB.
// Swizzle (T2): logical (row, col) lives at LDS elem row*64 + (col ^
// ((row&7)*8)). glds dest is linear, so the per-lane GLOBAL source col is
// pre-swizzled: 8*((L&7) ^ (L>>3)) (rule #21). Reads XOR the same term ->
// 8 consecutive rows hit 8 distinct 16B slots (2 lanes/bank = free, m136).
// Schedule (T3/T4/T5): ONE barrier per K-tile; own-glds vmcnt wait at tile
// top; tile t+1's 8 glds issued inside tile t's q2=0 phases; setprio(1)
// around MFMA runs. grid.x 0..11 -> Q (8) | K (2) | V (2); bijective XCD
// swizzle (192 blocks, 192 % 8 == 0).
// ===========================================================================
__global__ __launch_bounds__(512, 2) void qkv_gemm8(const u16* __restrict__ xb,
                                                    const u16* __restrict__ wqb,
                                                    const u16* __restrict__ wkb,
                                                    const u16* __restrict__ wvb,
                                                    u16* __restrict__ Qb,
                                                    u16* __restrict__ Kb,
                                                    u16* __restrict__ Vb) {
    __shared__ __align__(16) u16 Ash[2][256 * 64];   // 64 KiB
    __shared__ __align__(16) u16 Bsh[2][256 * 64];   // 64 KiB

    const int flat = blockIdx.y * 12 + blockIdx.x;
    const int nf   = (flat & 7) * 24 + (flat >> 3);
    const int ct   = nf % 12;
    const int rt   = nf / 12;
    const int rowBase = rt * 256;

    const u16* W; u16* C; int colBase, N; bool rope;
    if (ct < 8)       { W = wqb; C = Qb; colBase = ct * 256;        N = DIMC;  rope = true; }
    else if (ct < 10) { W = wkb; C = Kb; colBase = (ct - 8) * 256;  N = KVDIM; rope = true; }
    else              { W = wvb; C = Vb; colBase = (ct - 10) * 256; N = KVDIM; rope = false; }

    const int tid  = threadIdx.x;
    const int lane = tid & 63;
    const int wid  = tid >> 6;           // wave 0..7
    const int quad = lane >> 4;
    const int ln   = lane & 15;
    const int wr   = wid >> 2;           // 0..1  (M half: 128 rows)
    const int wc   = wid & 3;            // 0..3  (N quarter: 64 cols)

    // staging: wave wid owns 8-row chunks {wid + 8r}, r=0..3 (A and B each).
    const int sr = lane >> 3;
    const int sc = 8 * ((lane & 7) ^ sr);
    const u16* aS = xb + (size_t)(rowBase + wid * 8 + sr) * DIMC + sc;
    const u16* bS = W  + (size_t)(colBase + wid * 8 + sr) * DIMC + sc;

    f32x4 acc[8][4] = {};
    constexpr int NT = DIMC / 64;        // 32 K-tiles

    // prologue: stage tile 0 -> buf 0 (8 glds/thread)
    #pragma unroll
    for (int r = 0; r < 4; ++r) {
        glds16(aS + (size_t)r * 64 * DIMC, &Ash[0][(wid + 8 * r) * 512]);
        glds16(bS + (size_t)r * 64 * DIMC, &Bsh[0][(wid + 8 * r) * 512]);
    }

    for (int t = 0; t < NT; ++t) {
        const int cb = t & 1;
        __asm__ __volatile__("s_waitcnt vmcnt(0)" ::: "memory");
        __builtin_amdgcn_sched_barrier(0);
        __builtin_amdgcn_s_barrier();

        const u16* Ap = &Ash[cb][0];
        const u16* Bp = &Bsh[cb][0];
        u16* An = &Ash[cb ^ 1][0];
        u16* Bn = &Bsh[cb ^ 1][0];
        const bool pf = (t + 1 < NT);
        const size_t ko = (size_t)(t + 1) * 64;
        const int swz = (ln & 7) * 8;

        #pragma unroll
        for (int q2 = 0; q2 < 2; ++q2) {
            bf16x8 bwf[4];
            #pragma unroll
            for (int n = 0; n < 4; ++n) {
                const int row = wc * 64 + n * 16 + ln;
                bwf[n] = *(const bf16x8*)(Bp + row * 64 + ((q2 * 32 + quad * 8) ^ swz));
            }
            if (q2 == 0 && pf) {          // stage first half of tile t+1
                #pragma unroll
                for (int r = 0; r < 2; ++r) {
                    glds16(aS + ko + (size_t)r * 64 * DIMC, An + (wid + 8 * r) * 512);
                    glds16(bS + ko + (size_t)r * 64 * DIMC, Bn + (wid + 8 * r) * 512);
                }
                __builtin_amdgcn_sched_barrier(0);
            }
            #pragma unroll
            for (int mh = 0; mh < 2; ++mh) {
                __builtin_amdgcn_s_setprio(1);
                #pragma unroll
                for (int m = mh * 4; m < mh * 4 + 4; ++m) {
                    const int row = wr * 128 + m * 16 + ln;
                    bf16x8 af = *(const bf16x8*)(Ap + row * 64 + ((q2 * 32 + quad * 8) ^ swz));
                    #pragma unroll
                    for (int n = 0; n < 4; ++n)
                        acc[m][n] = __builtin_amdgcn_mfma_f32_16x16x32_bf16(af, bwf[n], acc[m][n], 0, 0, 0);
                }
                __builtin_amdgcn_s_setprio(0);
                if (q2 == 0 && mh == 0 && pf) {   // stage second half of t+1
                    #pragma unroll
                    for (int r = 2; r < 4; ++r) {
                        glds16(aS + ko + (size_t)r * 64 * DIMC, An + (wid + 8 * r) * 512);
                        glds16(bS + ko + (size_t)r * 64 * DIMC, Bn + (wid + 8 * r) * 512);
                    }
                    __builtin_amdgcn_sched_barrier(0);
                }
            }
        }
    }

    if (rope) {
        // head-local d = n*16+ln; pairs (d, d+32) -> (acc[m][n], acc[m][n+2])
        #pragma unroll
        for (int n = 0; n < 2; ++n) {
            const int d = n * 16 + ln;
            const float invrev = exp2f(-(float)d * (13.287712379549449f / 32.0f))
                                 * 0.15915494309189535f;   // /2pi
            #pragma unroll
            for (int m = 0; m < 8; ++m) {
                #pragma unroll
                for (int r = 0; r < 4; ++r) {
                    const int tt = (rowBase + wr * 128 + m * 16 + quad * 4 + r) & (T_SEQ - 1);
                    float rev = (float)tt * invrev;
                    float fr = rev - floorf(rev);
                    float sn = __builtin_amdgcn_sinf(fr);
                    float cs = __builtin_amdgcn_cosf(fr);
                    float a0 = acc[m][n][r], a2 = acc[m][n + 2][r];
                    acc[m][n][r]     = a0 * cs - a2 * sn;
                    acc[m][n + 2][r] = a2 * cs + a0 * sn;
                }
            }
        }
    }

    #pragma unroll
    for (int m = 0; m < 8; ++m) {
        const int mrow = rowBase + wr * 128 + m * 16 + quad * 4;
        #pragma unroll
        for (int n = 0; n < 4; ++n) {
            const int col = colBase + wc * 64 + n * 16 + ln;
            #pragma unroll
            for (int r = 0; r < 4; ++r)
                C[(size_t)(mrow + r) * N + col] = f2bf(acc[m][n][r]);
        }
    }
}

// ===========================================================================
// O-projection GEMM: 128x64 tiles -> 1024 blocks = 4/CU. R10: + XCD swizzle.
// ===========================================================================
__global__ __launch_bounds__(256, 4) void gemm_out64(const u16* __restrict__ A,
                                                     const u16* __restrict__ W,
                                                     float* __restrict__ C) {
    __shared__ __align__(16) u16 As[2 * 128 * 32];   // 16 KB
    __shared__ __align__(16) u16 Bs[2 * 64 * 32];    //  8 KB

    const int tid  = threadIdx.x;
    const int lane = tid & 63;
    const int w    = tid >> 6;
    const int quad = lane >> 4;
    const int ln   = lane & 15;

    const int flat = blockIdx.y * 32 + blockIdx.x;
    const int nf   = (flat & 7) * 128 + (flat >> 3);
    const int rowBase = (nf >> 5) * 128;
    const int colBase = (nf & 31) * 64;
    const int wm = w * 32;
    constexpr int K = DIMC, N = DIMC;

    f32x4 acc[2][4] = {};

    const int srow = lane >> 2;
    const int scol = (lane & 3) * 8;
    const u16* aC0 = A + (size_t)(rowBase + w * 16 + srow) * K + scol;
    const u16* aC1 = A + (size_t)(rowBase + (w + 4) * 16 + srow) * K + scol;
    const u16* bC  = W + (size_t)(colBase + w * 16 + srow) * K + scol;
    u16* asl0 = As + w * 512;
    u16* asl1 = As + (w + 4) * 512;
    u16* bsl  = Bs + w * 512;

    for (int kk = 0; kk < K; kk += 64) {
        __syncthreads();
        glds16(aC0 + kk, asl0);
        glds16(aC1 + kk, asl1);
        glds16(bC  + kk, bsl);
        glds16(aC0 + kk + 32, asl0 + 4096);
        glds16(aC1 + kk + 32, asl1 + 4096);
        glds16(bC  + kk + 32, bsl + 2048);
        __syncthreads();

        #pragma unroll
        for (int hp = 0; hp < 2; ++hp) {
            const u16* Ap = As + hp * 4096;
            const u16* Bp = Bs + hp * 2048;
            bf16x8 bw[4];
            #pragma unroll
            for (int j = 0; j < 4; ++j)
                bw[j] = *(const bf16x8*)(Bp + (j * 16 + ln) * 32 + quad * 8);
            #pragma unroll
            for (int i = 0; i < 2; ++i) {
                bf16x8 af = *(const bf16x8*)(Ap + (wm + i * 16 + ln) * 32 + quad * 8);
                #pragma unroll
                for (int j = 0; j < 4; ++j)
                    acc[i][j] = __builtin_amdgcn_mfma_f32_16x16x32_bf16(af, bw[j], acc[i][j], 0, 0, 0);
            }
        }
    }

    #pragma unroll
    for (int i = 0; i < 2; ++i) {
        int mrow = rowBase + wm + i * 16 + quad * 4;
        #pragma unroll
        for (int j = 0; j < 4; ++j) {
            int n = colBase + j * 16 + ln;
            #pragma unroll
            for (int r = 0; r < 4; ++r)
                C[(size_t)(mrow + r) * N + n] = acc[i][j][r];
        }
    }
}

// ===========================================================================
// V [B*T][KVDIM] -> Vt [B][KVDIM][T]
// ===========================================================================
__global__ __launch_bounds__(256) void transpose_v(const u16* __restrict__ V,
                                                   u16* __restrict__ Vt) {
    __shared__ __align__(16) u16 tile[32][33];
    const int x = threadIdx.x & 31;
    const int y = threadIdx.x >> 5;
    const int tok0 = blockIdx.y * 32;
    const int c0   = blockIdx.x * 32;
    #pragma unroll
    for (int yy = 0; yy < 32; yy += 8)
        tile[y + yy][x] = V[(size_t)(tok0 + y + yy) * KVDIM + c0 + x];
    __syncthreads();
    const int b  = tok0 >> 11;
    const int t0 = tok0 & (T_SEQ - 1);
    #pragma unroll
    for (int yy = 0; yy < 32; yy += 8)
        Vt[(size_t)(b * KVDIM + c0 + y + yy) * T_SEQ + t0 + x] = tile[x][y + yy];
}

// ===========================================================================
// Flash attention. grid = (16, NH, B), block = 256 (4 waves).
// R8: swapped QK^T (D[key][q]) + key->slot permutation
//   slot(k) = 32*(k>>5) + 8*((k>>2)&3) + 4*((k>>4)&1) + (k&3)
// R9: T14 async-STAGE pipeline + raw s_barrier + T5 setprio.
// ===========================================================================
__global__ __launch_bounds__(256) void attn(const u16* __restrict__ Q,
                                            const u16* __restrict__ Kx,
                                            const u16* __restrict__ Vt,
                                            u16* __restrict__ O) {
    __shared__ __align__(16) u16 Ks[64][72];       // [key][dim]
    __shared__ __align__(16) u16 Vs[64][72];       // [dim][slot]

    const int tid  = threadIdx.x;
    const int lane = tid & 63;
    const int w    = tid >> 6;
    const int quad = lane >> 4;
    const int ln   = lane & 15;
    const int h    = blockIdx.y;
    const int b    = blockIdx.z;
    const int kvh  = h >> 2;

    const int srow = tid >> 2;           // 0..63
    const int c    = tid & 3;
    const int scol = c * 16;             // token group base (16 tokens)
    const int vsb  = 32 * (c >> 1) + 4 * (c & 1);
    const u16* kbase = Kx + (size_t)(b * T_SEQ + srow) * KVDIM + kvh * HDIM + scol;
    const u16* vbase = Vt + (size_t)(b * KVDIM + kvh * HDIM + srow) * T_SEQ;

    const float K1 = 0.125f * 1.4426950408889634f;   // scale * log2(e)
    const float K2 = 8.0f * 1.4426950408889634f;     // M0 * log2(e)

    #pragma unroll
    for (int phase = 0; phase < 2; ++phase) {
        const int qt = phase ? (31 - (int)blockIdx.x) : (int)blockIdx.x;
        const int qr0 = qt * 64 + w * 16;

        const u16* qp = Q + (size_t)(b * T_SEQ + qr0 + ln) * DIMC + h * HDIM + quad * 8;
        const bf16x8 bq0 = *(const bf16x8*)qp;        // B-operand: col = q = ln
        const bf16x8 bq1 = *(const bf16x8*)(qp + 32);

        f32x4 o[4] = {};
        float lsum = 0.0f;

        bf16x8 kra = *(const bf16x8*)kbase;
        bf16x8 krb = *(const bf16x8*)(kbase + 8);
        bf16x8 vra = *(const bf16x8*)(vbase + scol);
        bf16x8 vrb = *(const bf16x8*)(vbase + scol + 8);

        for (int kt = 0; kt <= qt; ++kt) {
            __syncthreads();

            *(bf16x8*)&Ks[srow][scol]     = kra;
            *(bf16x8*)&Ks[srow][scol + 8] = krb;
            {   // V staging, slot-permuted: 4x ds_write_b64
                union { bf16x8 v; u16x4 h4[2]; } ua, ub;
                ua.v = vra; ub.v = vrb;
                *(u16x4*)&Vs[srow][vsb]      = ua.h4[0];
                *(u16x4*)&Vs[srow][vsb + 8]  = ua.h4[1];
                *(u16x4*)&Vs[srow][vsb + 16] = ub.h4[0];
                *(u16x4*)&Vs[srow][vsb + 24] = ub.h4[1];
            }

            if (kt < qt) {
                const size_t ko = (size_t)(kt + 1) * 64;
                kra = *(const bf16x8*)(kbase + ko * KVDIM);
                krb = *(const bf16x8*)(kbase + ko * KVDIM + 8);
                vra = *(const bf16x8*)(vbase + ko + scol);
                vrb = *(const bf16x8*)(vbase + ko + scol + 8);
            }

            __asm__ __volatile__("s_waitcnt lgkmcnt(0)" ::: "memory");
            __builtin_amdgcn_s_barrier();

            f32x4 s[4];
            __builtin_amdgcn_s_setprio(1);
            #pragma unroll
            for (int st = 0; st < 4; ++st) {
                f32x4 z = {};
                s[st] = __builtin_amdgcn_mfma_f32_16x16x32_bf16(
                            *(const bf16x8*)&Ks[st * 16 + ln][quad * 8], bq0, z, 0, 0, 0);
                s[st] = __builtin_amdgcn_mfma_f32_16x16x32_bf16(
                            *(const bf16x8*)&Ks[st * 16 + ln][32 + quad * 8], bq1, s[st], 0, 0, 0);
            }
            __builtin_amdgcn_s_setprio(0);

            unsigned int pk[8];
            if (kt != qt) {
                #pragma unroll
                for (int st = 0; st < 4; ++st) {
                    float e0 = exp2f(fmaf(s[st][0], K1, -K2));
                    float e1 = exp2f(fmaf(s[st][1], K1, -K2));
                    float e2 = exp2f(fmaf(s[st][2], K1, -K2));
                    float e3 = exp2f(fmaf(s[st][3], K1, -K2));
                    lsum += (e0 + e1) + (e2 + e3);
                    pk[2 * st]     = pack2_bf16(e0, e1);
                    pk[2 * st + 1] = pack2_bf16(e2, e3);
                }
            } else {
                const int thr = w * 16 + ln;            // q local in 64-block
                #pragma unroll
                for (int st = 0; st < 4; ++st) {
                    float e[4];
                    #pragma unroll
                    for (int r = 0; r < 4; ++r) {
                        const int key = st * 16 + quad * 4 + r;
                        e[r] = (key > thr) ? 0.0f : exp2f(fmaf(s[st][r], K1, -K2));
                    }
                    lsum += (e[0] + e[1]) + (e[2] + e[3]);
                    pk[2 * st]     = pack2_bf16(e[0], e[1]);
                    pk[2 * st + 1] = pack2_bf16(e[2], e[3]);
                }
            }

            union { unsigned int u[4]; bf16x8 v; } a0, a1;
            a0.u[0] = pk[0]; a0.u[1] = pk[1]; a0.u[2] = pk[2]; a0.u[3] = pk[3];
            a1.u[0] = pk[4]; a1.u[1] = pk[5]; a1.u[2] = pk[6]; a1.u[3] = pk[7];

            __builtin_amdgcn_s_setprio(1);
            #pragma unroll
            for (int t = 0; t < 4; ++t) {
                o[t] = __builtin_amdgcn_mfma_f32_16x16x32_bf16(
                           a0.v, *(const bf16x8*)&Vs[t * 16 + ln][quad * 8], o[t], 0, 0, 0);
                o[t] = __builtin_amdgcn_mfma_f32_16x16x32_bf16(
                           a1.v, *(const bf16x8*)&Vs[t * 16 + ln][32 + quad * 8], o[t], 0, 0, 0);
            }
            __builtin_amdgcn_s_setprio(0);
        }

        float ls = lsum;
        ls += __shfl_xor(ls, 16);
        ls += __shfl_xor(ls, 32);
        #pragma unroll
        for (int r = 0; r < 4; ++r) {
            const float inv = 1.0f / __shfl(ls, quad * 4 + r);
            size_t obase = (size_t)(b * T_SEQ + qr0 + quad * 4 + r) * DIMC + h * HDIM;
            #pragma unroll
            for (int t = 0; t < 4; ++t)
                O[obase + t * 16 + ln] = f2bf(o[t][r] * inv);
        }
    }
}

// ===========================================================================
extern "C" void kernel_launch(void* const* d_in, const int* in_sizes, int n_in,
                              void* d_out, int out_size, void* d_ws, size_t ws_size,
                              hipStream_t stream) {
    const float* x  = (const float*)d_in[0];
    const float* wq = (const float*)d_in[1];
    const float* wk = (const float*)d_in[2];
    const float* wv = (const float*)d_in[3];
    const float* wo = (const float*)d_in[4];
    float* out = (float*)d_out;

    char* ws = (char*)d_ws;
    constexpr size_t MB = 1024 * 1024;
    u16* Qb  = (u16*)(ws);             // 16 MB [4096][2048]
    u16* Kb  = (u16*)(ws + 16 * MB);   //  4 MB [4096][512]
    u16* Vb  = (u16*)(ws + 20 * MB);   //  4 MB [4096][512]
    u16* Vtb = (u16*)(ws + 24 * MB);   //  4 MB [2][512][2048]
    u16* AOb = (u16*)(ws + 28 * MB);   // 16 MB [4096][2048]  (aliases xb)
    u16* xb  = AOb;                    // x dead before attn writes AOb
    u16* wqb = (u16*)(ws + 44 * MB);   //  8 MB
    u16* wkb = (u16*)(ws + 52 * MB);   //  2 MB
    u16* wvb = (u16*)(ws + 54 * MB);   //  2 MB
    u16* wob = (u16*)(ws + 56 * MB);   //  8 MB
    const int M = BATCH * T_SEQ;       // 4096

    hipLaunchKernelGGL(cvt5, dim3(2048), dim3(256), 0, stream,
                       x, wq, wk, wv, wo, xb, wqb, wkb, wvb, wob);
    hipLaunchKernelGGL(qkv_gemm8, dim3(12, M / 256), dim3(512), 0, stream,
                       xb, wqb, wkb, wvb, Qb, Kb, Vb);
    hipLaunchKernelGGL(transpose_v, dim3(KVDIM / 32, M / 32), dim3(256), 0, stream, Vb, Vtb);
    hipLaunchKernelGGL(attn, dim3(16, NHEAD, BATCH), dim3(256), 0, stream,
                       Qb, Kb, Vtb, AOb);
    hipLaunchKernelGGL(gemm_out64, dim3(DIMC / 64, M / 128), dim3(256), 0, stream,
                       AOb, wob, out);
}

// Round 5
// 297.292 us; speedup vs baseline: 1.0752x; 1.0042x over previous
//
#include <hip/hip_runtime.h>

// Attention_6219112645023 — fp32 in / fp32 out, bf16 internal compute (MFMA).
// B=2, T=2048, DIM=2048, NH=32, NKV=8, HD=64. Causal GQA + RoPE + projections.
// Pipeline: cvt5 -> qkv_gemm -> transpose(V) -> flash attn -> O gemm.
// R8: attn — swapped QK^T + key-slot permutation, P stays in registers.
// R9: attn — T14 async-STAGE pipeline + raw s_barrier (no vmcnt drain) + T5.
// R10 lesson: 256^2 tile -> 192 blocks < 256 CUs + 1 block/CU = regression.
//   (but: XOR swizzle -> bank conflicts 0, XCD swizzle -> FETCH -23%. Keep.)
// R11: both GEMMs on a unified 128x128 / BK=64 / 4-wave DBUF core:
//   - double-buffered LDS (64 KiB -> 2 blocks/CU, inter-block overlap)
//   - ONE barrier per K-tile; prefetch glds issued right after the barrier,
//     so the vmcnt(0) for them lands a FULL tile of compute later
//   - XOR-swizzled LDS reads, inverse-swizzled glds SOURCE (linear dest)
//   - setprio(1) around MFMA runs, bijective XCD swizzle on the flat grid
//   O-projection promoted 128x64 -> 128x128 tile (acc 4x4, 2x MFMA/ds_read).
// R12: identical resubmission of R11 (previous bench = container infra
// failure, no kernel data; hang-hazard audit found no defect).

typedef unsigned short u16;
typedef __attribute__((ext_vector_type(8))) short bf16x8;  // 8 bf16 in 4 VGPRs
typedef __attribute__((ext_vector_type(4))) float f32x4;
typedef __attribute__((ext_vector_type(4))) unsigned short u16x4;

constexpr int T_SEQ = 2048;
constexpr int DIMC  = 2048;
constexpr int NHEAD = 32;
constexpr int HDIM  = 64;
constexpr int KVDIM = 512;   // NKV * HDIM
constexpr int BATCH = 2;

__device__ __forceinline__ u16 f2bf(float f) {
    union { float f; unsigned int i; } v; v.f = f;
    unsigned int r = v.i + 0x7FFFu + ((v.i >> 16) & 1u);   // RNE
    return (u16)(r >> 16);
}

// pack two f32 -> (bf16 lo = e0, bf16 hi = e1), truncating (P in [0,1]).
__device__ __forceinline__ unsigned int pack2_bf16(float e0, float e1) {
    return __builtin_amdgcn_perm(__float_as_uint(e1), __float_as_uint(e0),
                                 0x07060302u);
}

typedef __attribute__((address_space(1))) unsigned int as1_uint;
typedef __attribute__((address_space(3))) unsigned int as3_uint;
__device__ __forceinline__ void glds16(const u16* g, u16* l) {
    // async global->LDS, 16B/lane; LDS dest = wave-uniform base + lane*16
    __builtin_amdgcn_global_load_lds((as1_uint*)(u16*)g, (as3_uint*)l, 16, 0, 0);
}

// ===========================================================================
// Fused fp32->bf16 convert of all 5 inputs (one launch).
// ===========================================================================
__global__ __launch_bounds__(256) void cvt5(const float* __restrict__ x,
                                            const float* __restrict__ wq,
                                            const float* __restrict__ wk,
                                            const float* __restrict__ wv,
                                            const float* __restrict__ wo,
                                            u16* __restrict__ xb,  u16* __restrict__ wqb,
                                            u16* __restrict__ wkb, u16* __restrict__ wvb,
                                            u16* __restrict__ wob) {
    constexpr int E0 = BATCH * T_SEQ * DIMC;          // 8388608
    constexpr int E1 = E0 + DIMC * DIMC;              // +4194304
    constexpr int E2 = E1 + KVDIM * DIMC;             // +1048576
    constexpr int E3 = E2 + KVDIM * DIMC;             // +1048576
    constexpr int E4 = E3 + DIMC * DIMC;              // 18874368 total
    for (int i = (blockIdx.x * 256 + threadIdx.x) * 4; i < E4; i += gridDim.x * 1024) {
        const float* s; u16* d; int off;
        if (i < E0)      { s = x;  d = xb;  off = 0;  }
        else if (i < E1) { s = wq; d = wqb; off = E0; }
        else if (i < E2) { s = wk; d = wkb; off = E1; }
        else if (i < E3) { s = wv; d = wvb; off = E2; }
        else             { s = wo; d = wob; off = E3; }
        f32x4 v = *(const f32x4*)(s + (i - off));
        u16x4 o;
        #pragma unroll
        for (int e = 0; e < 4; ++e) o[e] = f2bf(v[e]);
        *(u16x4*)(d + (i - off)) = o;
    }
}

// ===========================================================================
// DBUF GEMM core: C = A[M][K] . W[N][K]^T, bf16 in, 128x128 tile, BK=64,
// 256 threads (4 waves, 2x2; per-wave 64x64 = acc[4][4]).
// LDS: 2 bufs x (A 128x64 + B 128x64) = 64 KiB -> 2 blocks/CU.
//
// Swizzle (T2, R10-proven conflicts=0): logical (row, col) lives at LDS elem
//   row*64 + (col ^ ((row&7)*8)).  glds dest is linear (wave base + lane*16B),
//   so the per-lane GLOBAL source col is pre-swizzled: 8*((L&7) ^ (L>>3)).
//   Reads XOR the same term -> 8 consecutive rows hit 8 distinct 16B slots.
//
// Schedule: per K-tile { vmcnt(0) [loads issued a FULL tile ago]; barrier;
//   issue 8 glds for t+1 into other buf; ds_read + 32 MFMA on this buf }.
// Only ONE barrier per tile: top-of-t barrier guarantees every wave finished
// t-1's ds_reads (consumed before its MFMAs), so buf^1 is safe to overwrite.
// ===========================================================================
template <bool OUTF32>
__device__ __forceinline__ void dgemm_core(const u16* __restrict__ A,
                                           const u16* __restrict__ W,
                                           void* __restrict__ Cv,
                                           int rowBase, int colBase,
                                           int N, int K, bool rope) {
    __shared__ __align__(16) u16 Ash[2][128 * 64];   // 32 KiB
    __shared__ __align__(16) u16 Bsh[2][128 * 64];   // 32 KiB

    const int tid  = threadIdx.x;
    const int lane = tid & 63;
    const int w    = tid >> 6;           // 0..3
    const int quad = lane >> 4;
    const int ln   = lane & 15;
    const int wm   = (w >> 1) * 64;
    const int wn   = (w & 1) * 64;

    // staging: round r (0..3) covers rows 32r + w*8 + (L>>3); lane L's global
    // col elems = 8*((L&7) ^ (L>>3)) (inverse-swizzle of its linear LDS slot).
    const int sr = lane >> 3;            // 0..7
    const int sc = 8 * ((lane & 7) ^ sr);
    const u16* aS = A + (size_t)(rowBase + w * 8 + sr) * K + sc;
    const u16* bS = W + (size_t)(colBase + w * 8 + sr) * K + sc;

    f32x4 acc[4][4] = {};
    const int NT = K / 64;

    // prologue: stage tile 0 -> buf 0 (8 glds/thread)
    #pragma unroll
    for (int r = 0; r < 4; ++r) {
        glds16(aS + (size_t)(r * 32) * K, &Ash[0][(w + 4 * r) * 512]);
        glds16(bS + (size_t)(r * 32) * K, &Bsh[0][(w + 4 * r) * 512]);
    }

    for (int t = 0; t < NT; ++t) {
        const int cb = t & 1;
        // own tile-t loads done (issued one full tile of compute ago)
        __asm__ __volatile__("s_waitcnt vmcnt(0)" ::: "memory");
        __builtin_amdgcn_sched_barrier(0);
        __builtin_amdgcn_s_barrier();

        if (t + 1 < NT) {   // issue tile t+1 immediately -> max issue->wait gap
            const size_t ko = (size_t)(t + 1) * 64;
            u16* An = &Ash[cb ^ 1][0];
            u16* Bn = &Bsh[cb ^ 1][0];
            #pragma unroll
            for (int r = 0; r < 4; ++r) {
                glds16(aS + ko + (size_t)(r * 32) * K, An + (w + 4 * r) * 512);
                glds16(bS + ko + (size_t)(r * 32) * K, Bn + (w + 4 * r) * 512);
            }
            __builtin_amdgcn_sched_barrier(0);
        }

        const u16* Ap = &Ash[cb][0];
        const u16* Bp = &Bsh[cb][0];
        const int swz = (ln & 7) * 8;
        #pragma unroll
        for (int q2 = 0; q2 < 2; ++q2) {
            bf16x8 bwf[4];
            #pragma unroll
            for (int n = 0; n < 4; ++n)
                bwf[n] = *(const bf16x8*)(Bp + (wn + n * 16 + ln) * 64
                                             + ((q2 * 32 + quad * 8) ^ swz));
            __builtin_amdgcn_s_setprio(1);
            #pragma unroll
            for (int m = 0; m < 4; ++m) {
                bf16x8 af = *(const bf16x8*)(Ap + (wm + m * 16 + ln) * 64
                                                + ((q2 * 32 + quad * 8) ^ swz));
                #pragma unroll
                for (int n = 0; n < 4; ++n)
                    acc[m][n] = __builtin_amdgcn_mfma_f32_16x16x32_bf16(af, bwf[n], acc[m][n], 0, 0, 0);
            }
            __builtin_amdgcn_s_setprio(0);
        }
    }

    if (rope) {
        // head-local d = j*16+ln; pairs (d, d+32) -> (acc[i][j], acc[i][j+2]).
        #pragma unroll
        for (int j = 0; j < 2; ++j) {
            const int d = j * 16 + ln;
            const float invrev = exp2f(-(float)d * (13.287712379549449f / 32.0f))
                                 * 0.15915494309189535f;   // /2pi
            #pragma unroll
            for (int i = 0; i < 4; ++i) {
                #pragma unroll
                for (int r = 0; r < 4; ++r) {
                    const int t = (rowBase + wm + i * 16 + quad * 4 + r) & (T_SEQ - 1);
                    float rev = (float)t * invrev;
                    float fr = rev - floorf(rev);
                    float sn = __builtin_amdgcn_sinf(fr);
                    float cs = __builtin_amdgcn_cosf(fr);
                    float a0 = acc[i][j][r], a2 = acc[i][j + 2][r];
                    acc[i][j][r]     = a0 * cs - a2 * sn;
                    acc[i][j + 2][r] = a2 * cs + a0 * sn;
                }
            }
        }
    }

    #pragma unroll
    for (int i = 0; i < 4; ++i) {
        int mrow = rowBase + wm + i * 16 + quad * 4;
        #pragma unroll
        for (int j = 0; j < 4; ++j) {
            int n = colBase + wn + j * 16 + ln;
            #pragma unroll
            for (int r = 0; r < 4; ++r) {
                if constexpr (OUTF32)
                    ((float*)Cv)[(size_t)(mrow + r) * N + n] = acc[i][j][r];
                else
                    ((u16*)Cv)[(size_t)(mrow + r) * N + n] = f2bf(acc[i][j][r]);
            }
        }
    }
}

// Fused QKV: 24 col-tiles (Q 16 | K 4 | V 4) x 32 row-tiles = 768 blocks.
// Bijective XCD swizzle (768 % 8 == 0); consecutive nf share the A row-panel.
__global__ __launch_bounds__(256, 2) void qkv_gemm(const u16* __restrict__ xb,
                                                   const u16* __restrict__ wqb,
                                                   const u16* __restrict__ wkb,
                                                   const u16* __restrict__ wvb,
                                                   u16* __restrict__ Qb,
                                                   u16* __restrict__ Kb,
                                                   u16* __restrict__ Vb) {
    const int flat = blockIdx.y * 24 + blockIdx.x;
    const int nf   = (flat & 7) * 96 + (flat >> 3);
    const int ct   = nf % 24;
    const int rowBase = (nf / 24) * 128;

    const u16* W; u16* C; int colBase, N; bool rope;
    if (ct < 16)      { W = wqb; C = Qb; colBase = ct * 128;        N = DIMC;  rope = true; }
    else if (ct < 20) { W = wkb; C = Kb; colBase = (ct - 16) * 128; N = KVDIM; rope = true; }
    else              { W = wvb; C = Vb; colBase = (ct - 20) * 128; N = KVDIM; rope = false; }
    dgemm_core<false>(xb, W, C, rowBase, colBase, N, DIMC, rope);
}

// O-projection: 16 col-tiles x 32 row-tiles = 512 blocks, XCD-swizzled.
__global__ __launch_bounds__(256, 2) void gemm_out(const u16* __restrict__ A,
                                                   const u16* __restrict__ W,
                                                   float* __restrict__ C) {
    const int flat = blockIdx.y * 16 + blockIdx.x;
    const int nf   = (flat & 7) * 64 + (flat >> 3);
    const int colBase = (nf % 16) * 128;
    const int rowBase = (nf / 16) * 128;
    dgemm_core<true>(A, W, C, rowBase, colBase, DIMC, DIMC, false);
}

// ===========================================================================
// V [B*T][KVDIM] -> Vt [B][KVDIM][T]
// ===========================================================================
__global__ __launch_bounds__(256) void transpose_v(const u16* __restrict__ V,
                                                   u16* __restrict__ Vt) {
    __shared__ __align__(16) u16 tile[32][33];
    const int x = threadIdx.x & 31;
    const int y = threadIdx.x >> 5;
    const int tok0 = blockIdx.y * 32;
    const int c0   = blockIdx.x * 32;
    #pragma unroll
    for (int yy = 0; yy < 32; yy += 8)
        tile[y + yy][x] = V[(size_t)(tok0 + y + yy) * KVDIM + c0 + x];
    __syncthreads();
    const int b  = tok0 >> 11;
    const int t0 = tok0 & (T_SEQ - 1);
    #pragma unroll
    for (int yy = 0; yy < 32; yy += 8)
        Vt[(size_t)(b * KVDIM + c0 + y + yy) * T_SEQ + t0 + x] = tile[x][y + yy];
}

// ===========================================================================
// Flash attention. grid = (16, NH, B), block = 256 (4 waves).
// R8: swapped QK^T (D[key][q]) + key->slot permutation
//   slot(k) = 32*(k>>5) + 8*((k>>2)&3) + 4*((k>>4)&1) + (k&3)
// R9: T14 async-STAGE pipeline + raw s_barrier + T5 setprio.
// ===========================================================================
__global__ __launch_bounds__(256) void attn(const u16* __restrict__ Q,
                                            const u16* __restrict__ Kx,
                                            const u16* __restrict__ Vt,
                                            u16* __restrict__ O) {
    __shared__ __align__(16) u16 Ks[64][72];       // [key][dim]
    __shared__ __align__(16) u16 Vs[64][72];       // [dim][slot]

    const int tid  = threadIdx.x;
    const int lane = tid & 63;
    const int w    = tid >> 6;
    const int quad = lane >> 4;
    const int ln   = lane & 15;
    const int h    = blockIdx.y;
    const int b    = blockIdx.z;
    const int kvh  = h >> 2;

    const int srow = tid >> 2;           // 0..63
    const int c    = tid & 3;
    const int scol = c * 16;             // token group base (16 tokens)
    const int vsb  = 32 * (c >> 1) + 4 * (c & 1);
    const u16* kbase = Kx + (size_t)(b * T_SEQ + srow) * KVDIM + kvh * HDIM + scol;
    const u16* vbase = Vt + (size_t)(b * KVDIM + kvh * HDIM + srow) * T_SEQ;

    const float K1 = 0.125f * 1.4426950408889634f;   // scale * log2(e)
    const float K2 = 8.0f * 1.4426950408889634f;     // M0 * log2(e)

    #pragma unroll
    for (int phase = 0; phase < 2; ++phase) {
        const int qt = phase ? (31 - (int)blockIdx.x) : (int)blockIdx.x;
        const int qr0 = qt * 64 + w * 16;

        const u16* qp = Q + (size_t)(b * T_SEQ + qr0 + ln) * DIMC + h * HDIM + quad * 8;
        const bf16x8 bq0 = *(const bf16x8*)qp;        // B-operand: col = q = ln
        const bf16x8 bq1 = *(const bf16x8*)(qp + 32);

        f32x4 o[4] = {};
        float lsum = 0.0f;

        bf16x8 kra = *(const bf16x8*)kbase;
        bf16x8 krb = *(const bf16x8*)(kbase + 8);
        bf16x8 vra = *(const bf16x8*)(vbase + scol);
        bf16x8 vrb = *(const bf16x8*)(vbase + scol + 8);

        for (int kt = 0; kt <= qt; ++kt) {
            __syncthreads();

            *(bf16x8*)&Ks[srow][scol]     = kra;
            *(bf16x8*)&Ks[srow][scol + 8] = krb;
            {   // V staging, slot-permuted: 4x ds_write_b64
                union { bf16x8 v; u16x4 h4[2]; } ua, ub;
                ua.v = vra; ub.v = vrb;
                *(u16x4*)&Vs[srow][vsb]      = ua.h4[0];
                *(u16x4*)&Vs[srow][vsb + 8]  = ua.h4[1];
                *(u16x4*)&Vs[srow][vsb + 16] = ub.h4[0];
                *(u16x4*)&Vs[srow][vsb + 24] = ub.h4[1];
            }

            if (kt < qt) {
                const size_t ko = (size_t)(kt + 1) * 64;
                kra = *(const bf16x8*)(kbase + ko * KVDIM);
                krb = *(const bf16x8*)(kbase + ko * KVDIM + 8);
                vra = *(const bf16x8*)(vbase + ko + scol);
                vrb = *(const bf16x8*)(vbase + ko + scol + 8);
            }

            __asm__ __volatile__("s_waitcnt lgkmcnt(0)" ::: "memory");
            __builtin_amdgcn_s_barrier();

            f32x4 s[4];
            __builtin_amdgcn_s_setprio(1);
            #pragma unroll
            for (int st = 0; st < 4; ++st) {
                f32x4 z = {};
                s[st] = __builtin_amdgcn_mfma_f32_16x16x32_bf16(
                            *(const bf16x8*)&Ks[st * 16 + ln][quad * 8], bq0, z, 0, 0, 0);
                s[st] = __builtin_amdgcn_mfma_f32_16x16x32_bf16(
                            *(const bf16x8*)&Ks[st * 16 + ln][32 + quad * 8], bq1, s[st], 0, 0, 0);
            }
            __builtin_amdgcn_s_setprio(0);

            unsigned int pk[8];
            if (kt != qt) {
                #pragma unroll
                for (int st = 0; st < 4; ++st) {
                    float e0 = exp2f(fmaf(s[st][0], K1, -K2));
                    float e1 = exp2f(fmaf(s[st][1], K1, -K2));
                    float e2 = exp2f(fmaf(s[st][2], K1, -K2));
                    float e3 = exp2f(fmaf(s[st][3], K1, -K2));
                    lsum += (e0 + e1) + (e2 + e3);
                    pk[2 * st]     = pack2_bf16(e0, e1);
                    pk[2 * st + 1] = pack2_bf16(e2, e3);
                }
            } else {
                const int thr = w * 16 + ln;            // q local in 64-block
                #pragma unroll
                for (int st = 0; st < 4; ++st) {
                    float e[4];
                    #pragma unroll
                    for (int r = 0; r < 4; ++r) {
                        const int key = st * 16 + quad * 4 + r;
                        e[r] = (key > thr) ? 0.0f : exp2f(fmaf(s[st][r], K1, -K2));
                    }
                    lsum += (e[0] + e[1]) + (e[2] + e[3]);
                    pk[2 * st]     = pack2_bf16(e[0], e[1]);
                    pk[2 * st + 1] = pack2_bf16(e[2], e[3]);
                }
            }

            union { unsigned int u[4]; bf16x8 v; } a0, a1;
            a0.u[0] = pk[0]; a0.u[1] = pk[1]; a0.u[2] = pk[2]; a0.u[3] = pk[3];
            a1.u[0] = pk[4]; a1.u[1] = pk[5]; a1.u[2] = pk[6]; a1.u[3] = pk[7];

            __builtin_amdgcn_s_setprio(1);
            #pragma unroll
            for (int t = 0; t < 4; ++t) {
                o[t] = __builtin_amdgcn_mfma_f32_16x16x32_bf16(
                           a0.v, *(const bf16x8*)&Vs[t * 16 + ln][quad * 8], o[t], 0, 0, 0);
                o[t] = __builtin_amdgcn_mfma_f32_16x16x32_bf16(
                           a1.v, *(const bf16x8*)&Vs[t * 16 + ln][32 + quad * 8], o[t], 0, 0, 0);
            }
            __builtin_amdgcn_s_setprio(0);
        }

        float ls = lsum;
        ls += __shfl_xor(ls, 16);
        ls += __shfl_xor(ls, 32);
        #pragma unroll
        for (int r = 0; r < 4; ++r) {
            const float inv = 1.0f / __shfl(ls, quad * 4 + r);
            size_t obase = (size_t)(b * T_SEQ + qr0 + quad * 4 + r) * DIMC + h * HDIM;
            #pragma unroll
            for (int t = 0; t < 4; ++t)
                O[obase + t * 16 + ln] = f2bf(o[t][r] * inv);
        }
    }
}

// ===========================================================================
extern "C" void kernel_launch(void* const* d_in, const int* in_sizes, int n_in,
                              void* d_out, int out_size, void* d_ws, size_t ws_size,
                              hipStream_t stream) {
    const float* x  = (const float*)d_in[0];
    const float* wq = (const float*)d_in[1];
    const float* wk = (const float*)d_in[2];
    const float* wv = (const float*)d_in[3];
    const float* wo = (const float*)d_in[4];
    float* out = (float*)d_out;

    char* ws = (char*)d_ws;
    constexpr size_t MB = 1024 * 1024;
    u16* Qb  = (u16*)(ws);             // 16 MB [4096][2048]
    u16* Kb  = (u16*)(ws + 16 * MB);   //  4 MB [4096][512]
    u16* Vb  = (u16*)(ws + 20 * MB);   //  4 MB [4096][512]
    u16* Vtb = (u16*)(ws + 24 * MB);   //  4 MB [2][512][2048]
    u16* AOb = (u16*)(ws + 28 * MB);   // 16 MB [4096][2048]  (aliases xb)
    u16* xb  = AOb;                    // x dead before attn writes AOb
    u16* wqb = (u16*)(ws + 44 * MB);   //  8 MB
    u16* wkb = (u16*)(ws + 52 * MB);   //  2 MB
    u16* wvb = (u16*)(ws + 54 * MB);   //  2 MB
    u16* wob = (u16*)(ws + 56 * MB);   //  8 MB
    const int M = BATCH * T_SEQ;       // 4096

    hipLaunchKernelGGL(cvt5, dim3(2048), dim3(256), 0, stream,
                       x, wq, wk, wv, wo, xb, wqb, wkb, wvb, wob);
    hipLaunchKernelGGL(qkv_gemm, dim3(24, M / 128), dim3(256), 0, stream,
                       xb, wqb, wkb, wvb, Qb, Kb, Vb);
    hipLaunchKernelGGL(transpose_v, dim3(KVDIM / 32, M / 32), dim3(256), 0, stream, Vb, Vtb);
    hipLaunchKernelGGL(attn, dim3(16, NHEAD, BATCH), dim3(256), 0, stream,
                       Qb, Kb, Vtb, AOb);
    hipLaunchKernelGGL(gemm_out, dim3(DIMC / 128, M / 128), dim3(256), 0, stream,
                       AOb, wob, out);
}

// Round 6
// 288.781 us; speedup vs baseline: 1.1069x; 1.0295x over previous
//
#include <hip/hip_runtime.h>

// Attention_6219112645023 — fp32 in / fp32 out, bf16 internal compute (MFMA).
// B=2, T=2048, DIM=2048, NH=32, NKV=8, HD=64. Causal GQA + RoPE + projections.
// Pipeline: cvt5 -> qkv_gemm -> transpose(V) -> flash attn -> O gemm.
// R8: attn — swapped QK^T + key-slot permutation, P stays in registers.
// R9: attn — T14 async-STAGE reg pipeline + raw s_barrier + T5 setprio.
// R10 lesson: 256^2 tile -> grid underfill = regression (keep swizzles).
// R11: unified 128x128 / BK=64 / 4-wave DBUF core, conflicts = 0.
// R13: (a) GEMM core: never-drain counted vmcnt — barrier; issue t+1 glds;
//      s_waitcnt vmcnt(8) (t done, t+1 FLYING across barriers); barrier.
//      No vmcnt(0) in the main loop (T4, AITER pattern).
//      (b) attn: K/V double-buffered LDS (36 KB) -> ONE raw s_barrier per
//      kt (top __syncthreads removed; phase-boundary sync added).

typedef unsigned short u16;
typedef __attribute__((ext_vector_type(8))) short bf16x8;  // 8 bf16 in 4 VGPRs
typedef __attribute__((ext_vector_type(4))) float f32x4;
typedef __attribute__((ext_vector_type(4))) unsigned short u16x4;

constexpr int T_SEQ = 2048;
constexpr int DIMC  = 2048;
constexpr int NHEAD = 32;
constexpr int HDIM  = 64;
constexpr int KVDIM = 512;   // NKV * HDIM
constexpr int BATCH = 2;

__device__ __forceinline__ u16 f2bf(float f) {
    union { float f; unsigned int i; } v; v.f = f;
    unsigned int r = v.i + 0x7FFFu + ((v.i >> 16) & 1u);   // RNE
    return (u16)(r >> 16);
}

// pack two f32 -> (bf16 lo = e0, bf16 hi = e1), truncating (P in [0,1]).
__device__ __forceinline__ unsigned int pack2_bf16(float e0, float e1) {
    return __builtin_amdgcn_perm(__float_as_uint(e1), __float_as_uint(e0),
                                 0x07060302u);
}

typedef __attribute__((address_space(1))) unsigned int as1_uint;
typedef __attribute__((address_space(3))) unsigned int as3_uint;
__device__ __forceinline__ void glds16(const u16* g, u16* l) {
    // async global->LDS, 16B/lane; LDS dest = wave-uniform base + lane*16
    __builtin_amdgcn_global_load_lds((as1_uint*)(u16*)g, (as3_uint*)l, 16, 0, 0);
}

// ===========================================================================
// Fused fp32->bf16 convert of all 5 inputs (one launch).
// ===========================================================================
__global__ __launch_bounds__(256) void cvt5(const float* __restrict__ x,
                                            const float* __restrict__ wq,
                                            const float* __restrict__ wk,
                                            const float* __restrict__ wv,
                                            const float* __restrict__ wo,
                                            u16* __restrict__ xb,  u16* __restrict__ wqb,
                                            u16* __restrict__ wkb, u16* __restrict__ wvb,
                                            u16* __restrict__ wob) {
    constexpr int E0 = BATCH * T_SEQ * DIMC;          // 8388608
    constexpr int E1 = E0 + DIMC * DIMC;              // +4194304
    constexpr int E2 = E1 + KVDIM * DIMC;             // +1048576
    constexpr int E3 = E2 + KVDIM * DIMC;             // +1048576
    constexpr int E4 = E3 + DIMC * DIMC;              // 18874368 total
    for (int i = (blockIdx.x * 256 + threadIdx.x) * 4; i < E4; i += gridDim.x * 1024) {
        const float* s; u16* d; int off;
        if (i < E0)      { s = x;  d = xb;  off = 0;  }
        else if (i < E1) { s = wq; d = wqb; off = E0; }
        else if (i < E2) { s = wk; d = wkb; off = E1; }
        else if (i < E3) { s = wv; d = wvb; off = E2; }
        else             { s = wo; d = wob; off = E3; }
        f32x4 v = *(const f32x4*)(s + (i - off));
        u16x4 o;
        #pragma unroll
        for (int e = 0; e < 4; ++e) o[e] = f2bf(v[e]);
        *(u16x4*)(d + (i - off)) = o;
    }
}

// ===========================================================================
// DBUF GEMM core: C = A[M][K] . W[N][K]^T, bf16 in, 128x128 tile, BK=64,
// 256 threads (4 waves, 2x2; per-wave 64x64 = acc[4][4]).
// LDS: 2 bufs x (A 128x64 + B 128x64) = 64 KiB.
// Swizzle (R10/R11-proven conflicts=0): logical (row,col) at LDS elem
//   row*64 + (col ^ ((row&7)*8)); glds SOURCE col pre-swizzled (linear dest).
// R13 schedule per K-tile (never-drain counted vmcnt, T4):
//   s_barrier                    // all waves done READING buf cb^1 (tile t-1)
//   issue 8 glds t+1 -> cb^1     // safe to overwrite now
//   s_waitcnt vmcnt(8)           // tile t's 8 loads done; t+1's 8 STAY FLYING
//   s_barrier                    // tile t published to all waves
//   ds_read + 32 MFMA on buf cb
// The in-flight count never reaches 0 inside the loop.
// ===========================================================================
template <bool OUTF32>
__device__ __forceinline__ void dgemm_core(const u16* __restrict__ A,
                                           const u16* __restrict__ W,
                                           void* __restrict__ Cv,
                                           int rowBase, int colBase,
                                           int N, int K, bool rope) {
    __shared__ __align__(16) u16 Ash[2][128 * 64];   // 32 KiB
    __shared__ __align__(16) u16 Bsh[2][128 * 64];   // 32 KiB

    const int tid  = threadIdx.x;
    const int lane = tid & 63;
    const int w    = tid >> 6;           // 0..3
    const int quad = lane >> 4;
    const int ln   = lane & 15;
    const int wm   = (w >> 1) * 64;
    const int wn   = (w & 1) * 64;

    // staging: round r (0..3) covers rows 32r + w*8 + (L>>3); lane L's global
    // col elems = 8*((L&7) ^ (L>>3)) (inverse-swizzle of its linear LDS slot).
    const int sr = lane >> 3;            // 0..7
    const int sc = 8 * ((lane & 7) ^ sr);
    const u16* aS = A + (size_t)(rowBase + w * 8 + sr) * K + sc;
    const u16* bS = W + (size_t)(colBase + w * 8 + sr) * K + sc;

    f32x4 acc[4][4] = {};
    const int NT = K / 64;

    // prologue: stage tile 0 -> buf 0 (8 glds/thread)
    #pragma unroll
    for (int r = 0; r < 4; ++r) {
        glds16(aS + (size_t)(r * 32) * K, &Ash[0][(w + 4 * r) * 512]);
        glds16(bS + (size_t)(r * 32) * K, &Bsh[0][(w + 4 * r) * 512]);
    }

    for (int t = 0; t < NT; ++t) {
        const int cb = t & 1;
        __builtin_amdgcn_s_barrier();          // reads of buf cb^1 complete
        __builtin_amdgcn_sched_barrier(0);

        if (t + 1 < NT) {
            const size_t ko = (size_t)(t + 1) * 64;
            u16* An = &Ash[cb ^ 1][0];
            u16* Bn = &Bsh[cb ^ 1][0];
            #pragma unroll
            for (int r = 0; r < 4; ++r) {
                glds16(aS + ko + (size_t)(r * 32) * K, An + (w + 4 * r) * 512);
                glds16(bS + ko + (size_t)(r * 32) * K, Bn + (w + 4 * r) * 512);
            }
            __builtin_amdgcn_sched_barrier(0);
            __asm__ __volatile__("s_waitcnt vmcnt(8)" ::: "memory");  // t done, t+1 flying
        } else {
            __asm__ __volatile__("s_waitcnt vmcnt(0)" ::: "memory");  // epilogue drain
        }
        __builtin_amdgcn_sched_barrier(0);
        __builtin_amdgcn_s_barrier();          // tile t published

        const u16* Ap = &Ash[cb][0];
        const u16* Bp = &Bsh[cb][0];
        const int swz = (ln & 7) * 8;
        #pragma unroll
        for (int q2 = 0; q2 < 2; ++q2) {
            bf16x8 bwf[4];
            #pragma unroll
            for (int n = 0; n < 4; ++n)
                bwf[n] = *(const bf16x8*)(Bp + (wn + n * 16 + ln) * 64
                                             + ((q2 * 32 + quad * 8) ^ swz));
            __builtin_amdgcn_s_setprio(1);
            #pragma unroll
            for (int m = 0; m < 4; ++m) {
                bf16x8 af = *(const bf16x8*)(Ap + (wm + m * 16 + ln) * 64
                                                + ((q2 * 32 + quad * 8) ^ swz));
                #pragma unroll
                for (int n = 0; n < 4; ++n)
                    acc[m][n] = __builtin_amdgcn_mfma_f32_16x16x32_bf16(af, bwf[n], acc[m][n], 0, 0, 0);
            }
            __builtin_amdgcn_s_setprio(0);
        }
    }

    if (rope) {
        // head-local d = j*16+ln; pairs (d, d+32) -> (acc[i][j], acc[i][j+2]).
        #pragma unroll
        for (int j = 0; j < 2; ++j) {
            const int d = j * 16 + ln;
            const float invrev = exp2f(-(float)d * (13.287712379549449f / 32.0f))
                                 * 0.15915494309189535f;   // /2pi
            #pragma unroll
            for (int i = 0; i < 4; ++i) {
                #pragma unroll
                for (int r = 0; r < 4; ++r) {
                    const int t = (rowBase + wm + i * 16 + quad * 4 + r) & (T_SEQ - 1);
                    float rev = (float)t * invrev;
                    float fr = rev - floorf(rev);
                    float sn = __builtin_amdgcn_sinf(fr);
                    float cs = __builtin_amdgcn_cosf(fr);
                    float a0 = acc[i][j][r], a2 = acc[i][j + 2][r];
                    acc[i][j][r]     = a0 * cs - a2 * sn;
                    acc[i][j + 2][r] = a2 * cs + a0 * sn;
                }
            }
        }
    }

    #pragma unroll
    for (int i = 0; i < 4; ++i) {
        int mrow = rowBase + wm + i * 16 + quad * 4;
        #pragma unroll
        for (int j = 0; j < 4; ++j) {
            int n = colBase + wn + j * 16 + ln;
            #pragma unroll
            for (int r = 0; r < 4; ++r) {
                if constexpr (OUTF32)
                    ((float*)Cv)[(size_t)(mrow + r) * N + n] = acc[i][j][r];
                else
                    ((u16*)Cv)[(size_t)(mrow + r) * N + n] = f2bf(acc[i][j][r]);
            }
        }
    }
}

// Fused QKV: 24 col-tiles (Q 16 | K 4 | V 4) x 32 row-tiles = 768 blocks.
// Bijective XCD swizzle (768 % 8 == 0); consecutive nf share the A row-panel.
__global__ __launch_bounds__(256, 2) void qkv_gemm(const u16* __restrict__ xb,
                                                   const u16* __restrict__ wqb,
                                                   const u16* __restrict__ wkb,
                                                   const u16* __restrict__ wvb,
                                                   u16* __restrict__ Qb,
                                                   u16* __restrict__ Kb,
                                                   u16* __restrict__ Vb) {
    const int flat = blockIdx.y * 24 + blockIdx.x;
    const int nf   = (flat & 7) * 96 + (flat >> 3);
    const int ct   = nf % 24;
    const int rowBase = (nf / 24) * 128;

    const u16* W; u16* C; int colBase, N; bool rope;
    if (ct < 16)      { W = wqb; C = Qb; colBase = ct * 128;        N = DIMC;  rope = true; }
    else if (ct < 20) { W = wkb; C = Kb; colBase = (ct - 16) * 128; N = KVDIM; rope = true; }
    else              { W = wvb; C = Vb; colBase = (ct - 20) * 128; N = KVDIM; rope = false; }
    dgemm_core<false>(xb, W, C, rowBase, colBase, N, DIMC, rope);
}

// O-projection: 16 col-tiles x 32 row-tiles = 512 blocks, XCD-swizzled.
__global__ __launch_bounds__(256, 2) void gemm_out(const u16* __restrict__ A,
                                                   const u16* __restrict__ W,
                                                   float* __restrict__ C) {
    const int flat = blockIdx.y * 16 + blockIdx.x;
    const int nf   = (flat & 7) * 64 + (flat >> 3);
    const int colBase = (nf % 16) * 128;
    const int rowBase = (nf / 16) * 128;
    dgemm_core<true>(A, W, C, rowBase, colBase, DIMC, DIMC, false);
}

// ===========================================================================
// V [B*T][KVDIM] -> Vt [B][KVDIM][T]
// ===========================================================================
__global__ __launch_bounds__(256) void transpose_v(const u16* __restrict__ V,
                                                   u16* __restrict__ Vt) {
    __shared__ __align__(16) u16 tile[32][33];
    const int x = threadIdx.x & 31;
    const int y = threadIdx.x >> 5;
    const int tok0 = blockIdx.y * 32;
    const int c0   = blockIdx.x * 32;
    #pragma unroll
    for (int yy = 0; yy < 32; yy += 8)
        tile[y + yy][x] = V[(size_t)(tok0 + y + yy) * KVDIM + c0 + x];
    __syncthreads();
    const int b  = tok0 >> 11;
    const int t0 = tok0 & (T_SEQ - 1);
    #pragma unroll
    for (int yy = 0; yy < 32; yy += 8)
        Vt[(size_t)(b * KVDIM + c0 + y + yy) * T_SEQ + t0 + x] = tile[x][y + yy];
}

// ===========================================================================
// Flash attention. grid = (16, NH, B), block = 256 (4 waves).
// R8: swapped QK^T (D[key][q]) + key->slot permutation
//   slot(k) = 32*(k>>5) + 8*((k>>2)&3) + 4*((k>>4)&1) + (k&3)
// R9: T14 async-STAGE reg pipeline + T5 setprio.
// R13: K/V double-buffered (36 KB) -> ONE raw barrier per kt.
// Safety: writing buf cb at kt requires all waves' READS of buf cb (kt-2)
// complete; each wave's kt-1 lgkmcnt(0) drains its kt-2 reads before the
// kt-1 barrier, so passing that barrier proves it chip-wide.
// Phase boundary: __syncthreads() after epilogue (before next phase's
// first ds_write into buf 0, which may still be read by slow waves).
// ===========================================================================
__global__ __launch_bounds__(256) void attn(const u16* __restrict__ Q,
                                            const u16* __restrict__ Kx,
                                            const u16* __restrict__ Vt,
                                            u16* __restrict__ O) {
    __shared__ __align__(16) u16 Ks[2][64][72];    // [buf][key][dim]
    __shared__ __align__(16) u16 Vs[2][64][72];    // [buf][dim][slot]

    const int tid  = threadIdx.x;
    const int lane = tid & 63;
    const int w    = tid >> 6;
    const int quad = lane >> 4;
    const int ln   = lane & 15;
    const int h    = blockIdx.y;
    const int b    = blockIdx.z;
    const int kvh  = h >> 2;

    const int srow = tid >> 2;           // 0..63
    const int c    = tid & 3;
    const int scol = c * 16;             // token group base (16 tokens)
    const int vsb  = 32 * (c >> 1) + 4 * (c & 1);
    const u16* kbase = Kx + (size_t)(b * T_SEQ + srow) * KVDIM + kvh * HDIM + scol;
    const u16* vbase = Vt + (size_t)(b * KVDIM + kvh * HDIM + srow) * T_SEQ;

    const float K1 = 0.125f * 1.4426950408889634f;   // scale * log2(e)
    const float K2 = 8.0f * 1.4426950408889634f;     // M0 * log2(e)

    #pragma unroll
    for (int phase = 0; phase < 2; ++phase) {
        const int qt = phase ? (31 - (int)blockIdx.x) : (int)blockIdx.x;
        const int qr0 = qt * 64 + w * 16;

        const u16* qp = Q + (size_t)(b * T_SEQ + qr0 + ln) * DIMC + h * HDIM + quad * 8;
        const bf16x8 bq0 = *(const bf16x8*)qp;        // B-operand: col = q = ln
        const bf16x8 bq1 = *(const bf16x8*)(qp + 32);

        f32x4 o[4] = {};
        float lsum = 0.0f;

        // pipeline prologue: tile-0 staging loads into registers
        bf16x8 kra = *(const bf16x8*)kbase;
        bf16x8 krb = *(const bf16x8*)(kbase + 8);
        bf16x8 vra = *(const bf16x8*)(vbase + scol);
        bf16x8 vrb = *(const bf16x8*)(vbase + scol + 8);

        for (int kt = 0; kt <= qt; ++kt) {
            const int cb = kt & 1;

            *(bf16x8*)&Ks[cb][srow][scol]     = kra;
            *(bf16x8*)&Ks[cb][srow][scol + 8] = krb;
            {   // V staging, slot-permuted: 4x ds_write_b64
                union { bf16x8 v; u16x4 h4[2]; } ua, ub;
                ua.v = vra; ub.v = vrb;
                *(u16x4*)&Vs[cb][srow][vsb]      = ua.h4[0];
                *(u16x4*)&Vs[cb][srow][vsb + 8]  = ua.h4[1];
                *(u16x4*)&Vs[cb][srow][vsb + 16] = ub.h4[0];
                *(u16x4*)&Vs[cb][srow][vsb + 24] = ub.h4[1];
            }

            // prefetch tile kt+1 into regs — flies under this tile's compute
            if (kt < qt) {
                const size_t ko = (size_t)(kt + 1) * 64;
                kra = *(const bf16x8*)(kbase + ko * KVDIM);
                krb = *(const bf16x8*)(kbase + ko * KVDIM + 8);
                vra = *(const bf16x8*)(vbase + ko + scol);
                vrb = *(const bf16x8*)(vbase + ko + scol + 8);
            }

            // own LDS writes (and prior reads) drained, then ONE raw barrier
            __asm__ __volatile__("s_waitcnt lgkmcnt(0)" ::: "memory");
            __builtin_amdgcn_s_barrier();

            f32x4 s[4];
            __builtin_amdgcn_s_setprio(1);
            #pragma unroll
            for (int st = 0; st < 4; ++st) {
                f32x4 z = {};
                s[st] = __builtin_amdgcn_mfma_f32_16x16x32_bf16(
                            *(const bf16x8*)&Ks[cb][st * 16 + ln][quad * 8], bq0, z, 0, 0, 0);
                s[st] = __builtin_amdgcn_mfma_f32_16x16x32_bf16(
                            *(const bf16x8*)&Ks[cb][st * 16 + ln][32 + quad * 8], bq1, s[st], 0, 0, 0);
            }
            __builtin_amdgcn_s_setprio(0);

            unsigned int pk[8];
            if (kt != qt) {
                #pragma unroll
                for (int st = 0; st < 4; ++st) {
                    float e0 = exp2f(fmaf(s[st][0], K1, -K2));
                    float e1 = exp2f(fmaf(s[st][1], K1, -K2));
                    float e2 = exp2f(fmaf(s[st][2], K1, -K2));
                    float e3 = exp2f(fmaf(s[st][3], K1, -K2));
                    lsum += (e0 + e1) + (e2 + e3);
                    pk[2 * st]     = pack2_bf16(e0, e1);
                    pk[2 * st + 1] = pack2_bf16(e2, e3);
                }
            } else {
                const int thr = w * 16 + ln;            // q local in 64-block
                #pragma unroll
                for (int st = 0; st < 4; ++st) {
                    float e[4];
                    #pragma unroll
                    for (int r = 0; r < 4; ++r) {
                        const int key = st * 16 + quad * 4 + r;
                        e[r] = (key > thr) ? 0.0f : exp2f(fmaf(s[st][r], K1, -K2));
                    }
                    lsum += (e[0] + e[1]) + (e[2] + e[3]);
                    pk[2 * st]     = pack2_bf16(e[0], e[1]);
                    pk[2 * st + 1] = pack2_bf16(e[2], e[3]);
                }
            }

            union { unsigned int u[4]; bf16x8 v; } a0, a1;
            a0.u[0] = pk[0]; a0.u[1] = pk[1]; a0.u[2] = pk[2]; a0.u[3] = pk[3];
            a1.u[0] = pk[4]; a1.u[1] = pk[5]; a1.u[2] = pk[6]; a1.u[3] = pk[7];

            __builtin_amdgcn_s_setprio(1);
            #pragma unroll
            for (int t = 0; t < 4; ++t) {
                o[t] = __builtin_amdgcn_mfma_f32_16x16x32_bf16(
                           a0.v, *(const bf16x8*)&Vs[cb][t * 16 + ln][quad * 8], o[t], 0, 0, 0);
                o[t] = __builtin_amdgcn_mfma_f32_16x16x32_bf16(
                           a1.v, *(const bf16x8*)&Vs[cb][t * 16 + ln][32 + quad * 8], o[t], 0, 0, 0);
            }
            __builtin_amdgcn_s_setprio(0);
        }

        float ls = lsum;
        ls += __shfl_xor(ls, 16);
        ls += __shfl_xor(ls, 32);
        #pragma unroll
        for (int r = 0; r < 4; ++r) {
            const float inv = 1.0f / __shfl(ls, quad * 4 + r);
            size_t obase = (size_t)(b * T_SEQ + qr0 + quad * 4 + r) * DIMC + h * HDIM;
            #pragma unroll
            for (int t = 0; t < 4; ++t)
                O[obase + t * 16 + ln] = f2bf(o[t][r] * inv);
        }

        // phase boundary: next phase's first ds_writes must not race
        // this phase's last ds_reads on slow waves.
        __syncthreads();
    }
}

// ===========================================================================
extern "C" void kernel_launch(void* const* d_in, const int* in_sizes, int n_in,
                              void* d_out, int out_size, void* d_ws, size_t ws_size,
                              hipStream_t stream) {
    const float* x  = (const float*)d_in[0];
    const float* wq = (const float*)d_in[1];
    const float* wk = (const float*)d_in[2];
    const float* wv = (const float*)d_in[3];
    const float* wo = (const float*)d_in[4];
    float* out = (float*)d_out;

    char* ws = (char*)d_ws;
    constexpr size_t MB = 1024 * 1024;
    u16* Qb  = (u16*)(ws);             // 16 MB [4096][2048]
    u16* Kb  = (u16*)(ws + 16 * MB);   //  4 MB [4096][512]
    u16* Vb  = (u16*)(ws + 20 * MB);   //  4 MB [4096][512]
    u16* Vtb = (u16*)(ws + 24 * MB);   //  4 MB [2][512][2048]
    u16* AOb = (u16*)(ws + 28 * MB);   // 16 MB [4096][2048]  (aliases xb)
    u16* xb  = AOb;                    // x dead before attn writes AOb
    u16* wqb = (u16*)(ws + 44 * MB);   //  8 MB
    u16* wkb = (u16*)(ws + 52 * MB);   //  2 MB
    u16* wvb = (u16*)(ws + 54 * MB);   //  2 MB
    u16* wob = (u16*)(ws + 56 * MB);   //  8 MB
    const int M = BATCH * T_SEQ;       // 4096

    hipLaunchKernelGGL(cvt5, dim3(2048), dim3(256), 0, stream,
                       x, wq, wk, wv, wo, xb, wqb, wkb, wvb, wob);
    hipLaunchKernelGGL(qkv_gemm, dim3(24, M / 128), dim3(256), 0, stream,
                       xb, wqb, wkb, wvb, Qb, Kb, Vb);
    hipLaunchKernelGGL(transpose_v, dim3(KVDIM / 32, M / 32), dim3(256), 0, stream, Vb, Vtb);
    hipLaunchKernelGGL(attn, dim3(16, NHEAD, BATCH), dim3(256), 0, stream,
                       Qb, Kb, Vtb, AOb);
    hipLaunchKernelGGL(gemm_out, dim3(DIMC / 128, M / 128), dim3(256), 0, stream,
                       AOb, wob, out);
}